// Round 2
// baseline (1657.733 us; speedup 1.0000x reference)
//
#include <hip/hip_runtime.h>

// APPNP: h0 = relu(x@W1+b1)@W2+b2 ; 10x h = 0.99*SpMM(h) + 0.01*h
// bf16 MFMA GEMMs, on-device CSR build, gather SpMM with bf16 h storage.
// R4: two-phase bucket sort replaces random scatter_edges (8x write amp);
//     LDS cursors in pass B; 32-bit gather index in prop.
// R5: non-temporal colw loads in prop (keep per-XCD L2 for the random
//     h-row gathers; colw is stream-once per iteration, no reuse).
// R6: nt hints on the CSR-build stream buffers (tmp write/read, colw write)
//     — stream-once data, keep L2 clean. No structural changes; goal is
//     to recover a profile after two infra-failed rounds.

#define N_NODES 100000
#define N_EDGES 3200000
#define IN_F    512
#define HID_F   256
#define OUT_F   64
#define NBKT    ((N_NODES + 63) / 64)   // 1563 coarse buckets (row>>6)

typedef short bf16x8 __attribute__((ext_vector_type(8)));
typedef float f32x4  __attribute__((ext_vector_type(4)));
typedef int   i32x2  __attribute__((ext_vector_type(2)));
typedef unsigned int u32x2 __attribute__((ext_vector_type(2)));

__device__ __forceinline__ unsigned short f2bf(float f) {
    unsigned int u = __float_as_uint(f);
    unsigned int r = (u + 0x7FFFu + ((u >> 16) & 1u)) >> 16;  // RNE
    return (unsigned short)r;
}
__device__ __forceinline__ float bf2f(unsigned short h) {
    return __uint_as_float(((unsigned int)h) << 16);
}

// ---------------- weight cast+transpose ----------------
__global__ void cast_transpose_w1(const float* __restrict__ w, unsigned short* __restrict__ wt) {
    int idx = blockIdx.x * blockDim.x + threadIdx.x;   // over 512*256
    if (idx >= IN_F * HID_F) return;
    int k = idx / HID_F, n = idx % HID_F;
    wt[(size_t)n * IN_F + k] = f2bf(w[idx]);           // W1T [HID_F][IN_F]
}
__global__ void cast_transpose_w2(const float* __restrict__ w, unsigned short* __restrict__ wt) {
    int idx = blockIdx.x * blockDim.x + threadIdx.x;   // over 256*64
    if (idx >= HID_F * OUT_F) return;
    int k = idx / OUT_F, n = idx % OUT_F;
    wt[(size_t)n * HID_F + k] = f2bf(w[idx]);          // W2T [OUT_F][HID_F]
}

// ---------------- GEMM1: h1 = relu(x @ W1 + b1), bf16 out ----------------
__global__ __launch_bounds__(512) void gemm1(const float* __restrict__ x,
                                             const unsigned short* __restrict__ w1t,
                                             const float* __restrict__ b1,
                                             unsigned short* __restrict__ h1) {
    int tid  = threadIdx.x;
    int lane = tid & 63;
    int w    = tid >> 6;     // 0..7
    int wm   = w >> 2;       // 0..1
    int wn   = w & 3;        // 0..3
    int quad = lane >> 4;    // 0..3
    int lm   = lane & 15;
    int m0 = blockIdx.x * 64 + wm * 32;
    int n0 = wn * 64;

    f32x4 acc[2][4];
    for (int i = 0; i < 2; ++i)
        for (int j = 0; j < 4; ++j)
            acc[i][j] = (f32x4){0.f, 0.f, 0.f, 0.f};

    for (int kk = 0; kk < IN_F; kk += 32) {
        bf16x8 a[2], b[4];
        for (int i = 0; i < 2; ++i) {
            int m = m0 + i * 16 + lm;
            if (m > N_NODES - 1) m = N_NODES - 1;            // clamp loads, mask stores
            const float* ap = x + (size_t)m * IN_F + kk + quad * 8;
            float4 f0 = *(const float4*)ap;
            float4 f1 = *(const float4*)(ap + 4);
            union { bf16x8 v; unsigned short u[8]; } t;
            t.u[0] = f2bf(f0.x); t.u[1] = f2bf(f0.y); t.u[2] = f2bf(f0.z); t.u[3] = f2bf(f0.w);
            t.u[4] = f2bf(f1.x); t.u[5] = f2bf(f1.y); t.u[6] = f2bf(f1.z); t.u[7] = f2bf(f1.w);
            a[i] = t.v;
        }
        for (int j = 0; j < 4; ++j) {
            int n = n0 + j * 16 + lm;
            b[j] = *(const bf16x8*)(w1t + (size_t)n * IN_F + kk + quad * 8);
        }
        for (int i = 0; i < 2; ++i)
            for (int j = 0; j < 4; ++j)
                acc[i][j] = __builtin_amdgcn_mfma_f32_16x16x32_bf16(a[i], b[j], acc[i][j], 0, 0, 0);
    }

    for (int i = 0; i < 2; ++i)
        for (int j = 0; j < 4; ++j) {
            int n = n0 + j * 16 + lm;
            float bias = b1[n];
            for (int r = 0; r < 4; ++r) {
                int m = m0 + i * 16 + quad * 4 + r;   // C/D: row=(lane>>4)*4+reg, col=lane&15
                if (m < N_NODES) {
                    float v = acc[i][j][r] + bias;
                    v = v > 0.f ? v : 0.f;
                    h1[(size_t)m * HID_F + n] = f2bf(v);
                }
            }
        }
}

// ---------------- GEMM2: h0 = h1 @ W2 + b2, bf16 out ----------------
__global__ __launch_bounds__(256) void gemm2(const unsigned short* __restrict__ h1,
                                             const unsigned short* __restrict__ w2t,
                                             const float* __restrict__ b2,
                                             unsigned short* __restrict__ h0) {
    int tid  = threadIdx.x;
    int lane = tid & 63;
    int w    = tid >> 6;     // 0..3
    int wm   = w >> 1;       // 0..1
    int wn   = w & 1;        // 0..1
    int quad = lane >> 4;
    int lm   = lane & 15;
    int m0 = blockIdx.x * 64 + wm * 32;
    int n0 = wn * 32;

    f32x4 acc[2][2];
    for (int i = 0; i < 2; ++i)
        for (int j = 0; j < 2; ++j)
            acc[i][j] = (f32x4){0.f, 0.f, 0.f, 0.f};

    for (int kk = 0; kk < HID_F; kk += 32) {
        bf16x8 a[2], b[2];
        for (int i = 0; i < 2; ++i) {
            int m = m0 + i * 16 + lm;
            if (m > N_NODES - 1) m = N_NODES - 1;
            a[i] = *(const bf16x8*)(h1 + (size_t)m * HID_F + kk + quad * 8);
        }
        for (int j = 0; j < 2; ++j) {
            int n = n0 + j * 16 + lm;
            b[j] = *(const bf16x8*)(w2t + (size_t)n * HID_F + kk + quad * 8);
        }
        for (int i = 0; i < 2; ++i)
            for (int j = 0; j < 2; ++j)
                acc[i][j] = __builtin_amdgcn_mfma_f32_16x16x32_bf16(a[i], b[j], acc[i][j], 0, 0, 0);
    }

    for (int i = 0; i < 2; ++i)
        for (int j = 0; j < 2; ++j) {
            int n = n0 + j * 16 + lm;
            float bias = b2[n];
            for (int r = 0; r < 4; ++r) {
                int m = m0 + i * 16 + quad * 4 + r;
                if (m < N_NODES) {
                    float v = acc[i][j][r] + bias;
                    h0[(size_t)m * OUT_F + n] = f2bf(v);
                }
            }
        }
}

// ---------------- CSR build ----------------
__global__ void count_edges(const int* __restrict__ row, int* __restrict__ cnt) {
    int e = blockIdx.x * blockDim.x + threadIdx.x;
    if (e < N_EDGES) atomicAdd(&cnt[row[e]], 1);
}

// hierarchical scan: rowptr[i+1] = inclusive-prefix(cnt[0..i]), rowptr[0]=0
__global__ __launch_bounds__(256) void scan_local(const int* __restrict__ cnt,
                                                  int* __restrict__ rowptr,
                                                  int* __restrict__ bsum, int n) {
    __shared__ int wsum[4];
    int tid = threadIdx.x;
    int i = blockIdx.x * 256 + tid;
    int v = (i < n) ? cnt[i] : 0;
    int incl = v;
    for (int d = 1; d < 64; d <<= 1) {
        int t = __shfl_up(incl, d);
        if ((tid & 63) >= d) incl += t;
    }
    int wid = tid >> 6;
    if ((tid & 63) == 63) wsum[wid] = incl;
    __syncthreads();
    if (tid == 0) {
        int a = 0;
        for (int k = 0; k < 4; ++k) { int t = wsum[k]; wsum[k] = a; a += t; }
        bsum[blockIdx.x] = a;
    }
    __syncthreads();
    if (i < n) rowptr[i + 1] = incl + wsum[wid];   // block offset added later
}

__global__ __launch_bounds__(512) void scan_bsum(const int* __restrict__ bsum,
                                                 int* __restrict__ boff, int nb) {
    __shared__ int wsum[8];
    int tid = threadIdx.x;
    int v = (tid < nb) ? bsum[tid] : 0;
    int incl = v;
    for (int d = 1; d < 64; d <<= 1) {
        int t = __shfl_up(incl, d);
        if ((tid & 63) >= d) incl += t;
    }
    int wid = tid >> 6;
    if ((tid & 63) == 63) wsum[wid] = incl;
    __syncthreads();
    if (tid == 0) {
        int a = 0;
        for (int k = 0; k < 8; ++k) { int t = wsum[k]; wsum[k] = a; a += t; }
    }
    __syncthreads();
    if (tid < nb) boff[tid] = incl - v + wsum[wid];   // exclusive
}

__global__ __launch_bounds__(256) void scan_add(int* __restrict__ rowptr,
                                                const int* __restrict__ boff, int n) {
    int i = blockIdx.x * 256 + threadIdx.x;
    if (i == 0) rowptr[0] = 0;
    if (i < n) rowptr[i + 1] += boff[blockIdx.x];
}

// coarse-bucket cursor init: bucket c region starts at rowptr[64c].
// Counters padded to one per 64B line (stride 16 ints).
__global__ void ccur_init(const int* __restrict__ rowptr, int* __restrict__ ccur) {
    int c = blockIdx.x * blockDim.x + threadIdx.x;
    if (c < NBKT) ccur[c * 16] = rowptr[c * 64];
}

// Pass A: scatter edges to coarse buckets (row>>6). Payload packed 8B:
// x = col | (row&63)<<17, y = weight bits. Active write set = 1563 lines.
__global__ void bucket_scatter(const int* __restrict__ row, const int* __restrict__ col,
                               const float* __restrict__ ew, int* __restrict__ ccur,
                               uint2* __restrict__ tmp) {
    int e = blockIdx.x * blockDim.x + threadIdx.x;
    if (e < N_EDGES) {
        int r = row[e];
        int c = r >> 6;
        int p = atomicAdd(&ccur[c * 16], 1);
        u32x2 v; v.x = (unsigned)col[e] | ((unsigned)(r & 63) << 17);
        v.y = __float_as_uint(ew[e]);
        __builtin_nontemporal_store(v, (u32x2*)tmp + p);
    }
}

// Pass B: one block per bucket; LDS cursors for the 64 exclusively-owned
// rows; contiguous read of bucket region, write within 16KB span.
__global__ __launch_bounds__(256) void bucket_sort(const uint2* __restrict__ tmp,
                                                   const int* __restrict__ rowptr,
                                                   int2* __restrict__ colw) {
    __shared__ int lcur[64];
    int c = blockIdx.x;
    int r0 = c * 64;
    int tid = threadIdx.x;
    int rend = r0 + 64; if (rend > N_NODES) rend = N_NODES;
    if (tid < 64) {
        int rr = r0 + tid;
        lcur[tid] = (rr < N_NODES) ? rowptr[rr] : 0;
    }
    __syncthreads();
    int s = rowptr[r0];
    int e = rowptr[rend];
    const u32x2* tp = (const u32x2*)tmp;
    for (int i = s + tid; i < e; i += 256) {
        u32x2 t = __builtin_nontemporal_load(tp + i);
        int rl = (t.x >> 17) & 63;
        int cc = t.x & 0x1FFFF;
        int p = atomicAdd(&lcur[rl], 1);
        i32x2 v; v.x = cc; v.y = (int)t.y;
        __builtin_nontemporal_store(v, (i32x2*)colw + p);
    }
}

// ---------------- propagation ----------------
// One wave per row. 64 lanes = 8 edge-slots x 8 feature-octets.
// Lane (slot=lane>>3, fe=lane&7) handles features [8*fe, 8*fe+7] of edge
// slot: 16B bf16x8 gather per lane, 8 lanes cover a full 128B h-row.
// colw is loaded non-temporally: stream-once per iteration, keep L2 for h.
__global__ __launch_bounds__(256) void prop(const unsigned short* __restrict__ hin,
                                            const int* __restrict__ rowptr,
                                            const int2* __restrict__ colw,
                                            unsigned short* __restrict__ hout,
                                            float* __restrict__ fout, int is_final) {
    int lane = threadIdx.x & 63;
    int r = blockIdx.x * 4 + (threadIdx.x >> 6);
    int fe   = lane & 7;     // feature octet index
    int slot = lane >> 3;    // 0..7

    int s = rowptr[r];
    int e = rowptr[r + 1];
    const unsigned short* hfe = hin + 8 * fe;
    const i32x2* cwp = (const i32x2*)colw;

    float af[8];
    #pragma unroll
    for (int k = 0; k < 8; ++k) af[k] = 0.f;

    int n8 = (e - s) & ~7;
    int i = s;
    #pragma unroll 2
    for (; i < s + n8; i += 8) {
        i32x2 cw = __builtin_nontemporal_load(cwp + i + slot);
        float w = __int_as_float(cw.y);
        bf16x8 p = *(const bf16x8*)(hfe + (unsigned)cw.x * (unsigned)OUT_F);
        #pragma unroll
        for (int k = 0; k < 8; ++k)
            af[k] += w * bf2f((unsigned short)p[k]);
    }
    {   // tail (0..7 edges)
        int ei = i + slot;
        if (ei < e) {
            i32x2 cw = __builtin_nontemporal_load(cwp + ei);
            float w = __int_as_float(cw.y);
            bf16x8 p = *(const bf16x8*)(hfe + (unsigned)cw.x * (unsigned)OUT_F);
            #pragma unroll
            for (int k = 0; k < 8; ++k)
                af[k] += w * bf2f((unsigned short)p[k]);
        }
    }
    // combine the 8 edge-slots
    #pragma unroll
    for (int k = 0; k < 8; ++k) {
        af[k] += __shfl_xor(af[k], 8);
        af[k] += __shfl_xor(af[k], 16);
        af[k] += __shfl_xor(af[k], 32);
    }

    if (slot == 0) {
        bf16x8 ps = *(const bf16x8*)(hin + (unsigned)r * (unsigned)OUT_F + 8 * fe);
        float rr[8];
        #pragma unroll
        for (int k = 0; k < 8; ++k)
            rr[k] = 0.99f * af[k] + 0.01f * bf2f((unsigned short)ps[k]);
        size_t o = (size_t)r * OUT_F + 8 * fe;
        if (is_final) {
            *(float4*)(fout + o)     = make_float4(rr[0], rr[1], rr[2], rr[3]);
            *(float4*)(fout + o + 4) = make_float4(rr[4], rr[5], rr[6], rr[7]);
        } else {
            union { bf16x8 v; unsigned short u[8]; } pk;
            #pragma unroll
            for (int k = 0; k < 8; ++k) pk.u[k] = f2bf(rr[k]);
            *(bf16x8*)(hout + o) = pk.v;
        }
    }
}

extern "C" void kernel_launch(void* const* d_in, const int* in_sizes, int n_in,
                              void* d_out, int out_size, void* d_ws, size_t ws_size,
                              hipStream_t stream) {
    (void)in_sizes; (void)n_in; (void)out_size; (void)ws_size;
    const float* x  = (const float*)d_in[0];
    const float* W1 = (const float*)d_in[1];
    const float* b1 = (const float*)d_in[2];
    const float* W2 = (const float*)d_in[3];
    const float* b2 = (const float*)d_in[4];
    const float* ew = (const float*)d_in[5];
    const int*  row = (const int*)d_in[6];
    const int*  col = (const int*)d_in[7];
    float* out = (float*)d_out;

    char* ws = (char*)d_ws;
    size_t off = 0;
    auto alloc = [&](size_t b) { char* p = ws + off; off += (b + 255) & ~(size_t)255; return p; };
    unsigned short* w1t = (unsigned short*)alloc((size_t)IN_F * HID_F * 2);
    unsigned short* w2t = (unsigned short*)alloc((size_t)HID_F * OUT_F * 2);
    unsigned short* h1  = (unsigned short*)alloc((size_t)N_NODES * HID_F * 2);
    unsigned short* hb0 = (unsigned short*)alloc((size_t)N_NODES * OUT_F * 2);
    unsigned short* hb1 = (unsigned short*)alloc((size_t)N_NODES * OUT_F * 2);
    int*  rowptr = (int*)alloc((size_t)(N_NODES + 1) * 4);
    int*  cnt    = (int*)alloc((size_t)N_NODES * 4);
    int*  bsum   = (int*)alloc(512 * 4);
    int*  boff   = (int*)alloc(512 * 4);
    int*  ccur   = (int*)alloc((size_t)NBKT * 16 * 4);
    uint2* tmp   = (uint2*)alloc((size_t)N_EDGES * 8);
    int2* colw   = (int2*)alloc((size_t)N_EDGES * 8);

    const int NB = (N_NODES + 255) / 256;   // 391

    cast_transpose_w1<<<(IN_F * HID_F + 255) / 256, 256, 0, stream>>>(W1, w1t);
    cast_transpose_w2<<<(HID_F * OUT_F + 255) / 256, 256, 0, stream>>>(W2, w2t);
    gemm1<<<(N_NODES + 63) / 64, 512, 0, stream>>>(x, w1t, b1, h1);
    gemm2<<<(N_NODES + 63) / 64, 256, 0, stream>>>(h1, w2t, b2, hb0);

    hipMemsetAsync(cnt, 0, (size_t)N_NODES * 4, stream);
    count_edges<<<(N_EDGES + 255) / 256, 256, 0, stream>>>(row, cnt);
    scan_local<<<NB, 256, 0, stream>>>(cnt, rowptr, bsum, N_NODES);
    scan_bsum<<<1, 512, 0, stream>>>(bsum, boff, NB);
    scan_add<<<NB, 256, 0, stream>>>(rowptr, boff, N_NODES);
    ccur_init<<<(NBKT + 255) / 256, 256, 0, stream>>>(rowptr, ccur);
    bucket_scatter<<<(N_EDGES + 255) / 256, 256, 0, stream>>>(row, col, ew, ccur, tmp);
    bucket_sort<<<NBKT, 256, 0, stream>>>(tmp, rowptr, colw);

    const unsigned short* pin = hb0;
    for (int s = 0; s < 10; ++s) {
        int last = (s == 9);
        unsigned short* pout = (s & 1) ? hb0 : hb1;
        prop<<<N_NODES / 4, 256, 0, stream>>>(pin, rowptr, colw, pout, out, last);
        pin = pout;
    }
}

// Round 3
// 1584.413 us; speedup vs baseline: 1.0463x; 1.0463x over previous
//
#include <hip/hip_runtime.h>

// APPNP: h0 = relu(x@W1+b1)@W2+b2 ; 10x h = 0.99*SpMM(h) + 0.01*h
// bf16 MFMA GEMMs, on-device CSR build, gather SpMM with bf16 h storage.
// R4: two-phase bucket sort replaces random scatter_edges (8x write amp);
//     LDS cursors in pass B; 32-bit gather index in prop.
// R5: non-temporal colw loads in prop (keep per-XCD L2 for the random
//     h-row gathers; colw is stream-once per iteration, no reuse).
// R6: nt hints on CSR-build stream buffers. POST-MORTEM: nt STORES caused
//     8.75x write amplification in bucket_scatter (WRITE_SIZE 224 MB vs
//     25.6 MB payload, 260 us/dispatch) — nt bypasses exactly the L2
//     write-coalescing the bucket design relies on. REVERTED.
// R7: nt stores reverted to cached stores; nt LOADS kept (tmp in
//     bucket_sort, colw in prop — stream-once reads, no reuse).

#define N_NODES 100000
#define N_EDGES 3200000
#define IN_F    512
#define HID_F   256
#define OUT_F   64
#define NBKT    ((N_NODES + 63) / 64)   // 1563 coarse buckets (row>>6)

typedef short bf16x8 __attribute__((ext_vector_type(8)));
typedef float f32x4  __attribute__((ext_vector_type(4)));
typedef int   i32x2  __attribute__((ext_vector_type(2)));
typedef unsigned int u32x2 __attribute__((ext_vector_type(2)));

__device__ __forceinline__ unsigned short f2bf(float f) {
    unsigned int u = __float_as_uint(f);
    unsigned int r = (u + 0x7FFFu + ((u >> 16) & 1u)) >> 16;  // RNE
    return (unsigned short)r;
}
__device__ __forceinline__ float bf2f(unsigned short h) {
    return __uint_as_float(((unsigned int)h) << 16);
}

// ---------------- weight cast+transpose ----------------
__global__ void cast_transpose_w1(const float* __restrict__ w, unsigned short* __restrict__ wt) {
    int idx = blockIdx.x * blockDim.x + threadIdx.x;   // over 512*256
    if (idx >= IN_F * HID_F) return;
    int k = idx / HID_F, n = idx % HID_F;
    wt[(size_t)n * IN_F + k] = f2bf(w[idx]);           // W1T [HID_F][IN_F]
}
__global__ void cast_transpose_w2(const float* __restrict__ w, unsigned short* __restrict__ wt) {
    int idx = blockIdx.x * blockDim.x + threadIdx.x;   // over 256*64
    if (idx >= HID_F * OUT_F) return;
    int k = idx / OUT_F, n = idx % OUT_F;
    wt[(size_t)n * HID_F + k] = f2bf(w[idx]);          // W2T [OUT_F][HID_F]
}

// ---------------- GEMM1: h1 = relu(x @ W1 + b1), bf16 out ----------------
__global__ __launch_bounds__(512) void gemm1(const float* __restrict__ x,
                                             const unsigned short* __restrict__ w1t,
                                             const float* __restrict__ b1,
                                             unsigned short* __restrict__ h1) {
    int tid  = threadIdx.x;
    int lane = tid & 63;
    int w    = tid >> 6;     // 0..7
    int wm   = w >> 2;       // 0..1
    int wn   = w & 3;        // 0..3
    int quad = lane >> 4;    // 0..3
    int lm   = lane & 15;
    int m0 = blockIdx.x * 64 + wm * 32;
    int n0 = wn * 64;

    f32x4 acc[2][4];
    for (int i = 0; i < 2; ++i)
        for (int j = 0; j < 4; ++j)
            acc[i][j] = (f32x4){0.f, 0.f, 0.f, 0.f};

    for (int kk = 0; kk < IN_F; kk += 32) {
        bf16x8 a[2], b[4];
        for (int i = 0; i < 2; ++i) {
            int m = m0 + i * 16 + lm;
            if (m > N_NODES - 1) m = N_NODES - 1;            // clamp loads, mask stores
            const float* ap = x + (size_t)m * IN_F + kk + quad * 8;
            float4 f0 = *(const float4*)ap;
            float4 f1 = *(const float4*)(ap + 4);
            union { bf16x8 v; unsigned short u[8]; } t;
            t.u[0] = f2bf(f0.x); t.u[1] = f2bf(f0.y); t.u[2] = f2bf(f0.z); t.u[3] = f2bf(f0.w);
            t.u[4] = f2bf(f1.x); t.u[5] = f2bf(f1.y); t.u[6] = f2bf(f1.z); t.u[7] = f2bf(f1.w);
            a[i] = t.v;
        }
        for (int j = 0; j < 4; ++j) {
            int n = n0 + j * 16 + lm;
            b[j] = *(const bf16x8*)(w1t + (size_t)n * IN_F + kk + quad * 8);
        }
        for (int i = 0; i < 2; ++i)
            for (int j = 0; j < 4; ++j)
                acc[i][j] = __builtin_amdgcn_mfma_f32_16x16x32_bf16(a[i], b[j], acc[i][j], 0, 0, 0);
    }

    for (int i = 0; i < 2; ++i)
        for (int j = 0; j < 4; ++j) {
            int n = n0 + j * 16 + lm;
            float bias = b1[n];
            for (int r = 0; r < 4; ++r) {
                int m = m0 + i * 16 + quad * 4 + r;   // C/D: row=(lane>>4)*4+reg, col=lane&15
                if (m < N_NODES) {
                    float v = acc[i][j][r] + bias;
                    v = v > 0.f ? v : 0.f;
                    h1[(size_t)m * HID_F + n] = f2bf(v);
                }
            }
        }
}

// ---------------- GEMM2: h0 = h1 @ W2 + b2, bf16 out ----------------
__global__ __launch_bounds__(256) void gemm2(const unsigned short* __restrict__ h1,
                                             const unsigned short* __restrict__ w2t,
                                             const float* __restrict__ b2,
                                             unsigned short* __restrict__ h0) {
    int tid  = threadIdx.x;
    int lane = tid & 63;
    int w    = tid >> 6;     // 0..3
    int wm   = w >> 1;       // 0..1
    int wn   = w & 1;        // 0..1
    int quad = lane >> 4;
    int lm   = lane & 15;
    int m0 = blockIdx.x * 64 + wm * 32;
    int n0 = wn * 32;

    f32x4 acc[2][2];
    for (int i = 0; i < 2; ++i)
        for (int j = 0; j < 2; ++j)
            acc[i][j] = (f32x4){0.f, 0.f, 0.f, 0.f};

    for (int kk = 0; kk < HID_F; kk += 32) {
        bf16x8 a[2], b[2];
        for (int i = 0; i < 2; ++i) {
            int m = m0 + i * 16 + lm;
            if (m > N_NODES - 1) m = N_NODES - 1;
            a[i] = *(const bf16x8*)(h1 + (size_t)m * HID_F + kk + quad * 8);
        }
        for (int j = 0; j < 2; ++j) {
            int n = n0 + j * 16 + lm;
            b[j] = *(const bf16x8*)(w2t + (size_t)n * HID_F + kk + quad * 8);
        }
        for (int i = 0; i < 2; ++i)
            for (int j = 0; j < 2; ++j)
                acc[i][j] = __builtin_amdgcn_mfma_f32_16x16x32_bf16(a[i], b[j], acc[i][j], 0, 0, 0);
    }

    for (int i = 0; i < 2; ++i)
        for (int j = 0; j < 2; ++j) {
            int n = n0 + j * 16 + lm;
            float bias = b2[n];
            for (int r = 0; r < 4; ++r) {
                int m = m0 + i * 16 + quad * 4 + r;
                if (m < N_NODES) {
                    float v = acc[i][j][r] + bias;
                    h0[(size_t)m * OUT_F + n] = f2bf(v);
                }
            }
        }
}

// ---------------- CSR build ----------------
__global__ void count_edges(const int* __restrict__ row, int* __restrict__ cnt) {
    int e = blockIdx.x * blockDim.x + threadIdx.x;
    if (e < N_EDGES) atomicAdd(&cnt[row[e]], 1);
}

// hierarchical scan: rowptr[i+1] = inclusive-prefix(cnt[0..i]), rowptr[0]=0
__global__ __launch_bounds__(256) void scan_local(const int* __restrict__ cnt,
                                                  int* __restrict__ rowptr,
                                                  int* __restrict__ bsum, int n) {
    __shared__ int wsum[4];
    int tid = threadIdx.x;
    int i = blockIdx.x * 256 + tid;
    int v = (i < n) ? cnt[i] : 0;
    int incl = v;
    for (int d = 1; d < 64; d <<= 1) {
        int t = __shfl_up(incl, d);
        if ((tid & 63) >= d) incl += t;
    }
    int wid = tid >> 6;
    if ((tid & 63) == 63) wsum[wid] = incl;
    __syncthreads();
    if (tid == 0) {
        int a = 0;
        for (int k = 0; k < 4; ++k) { int t = wsum[k]; wsum[k] = a; a += t; }
        bsum[blockIdx.x] = a;
    }
    __syncthreads();
    if (i < n) rowptr[i + 1] = incl + wsum[wid];   // block offset added later
}

__global__ __launch_bounds__(512) void scan_bsum(const int* __restrict__ bsum,
                                                 int* __restrict__ boff, int nb) {
    __shared__ int wsum[8];
    int tid = threadIdx.x;
    int v = (tid < nb) ? bsum[tid] : 0;
    int incl = v;
    for (int d = 1; d < 64; d <<= 1) {
        int t = __shfl_up(incl, d);
        if ((tid & 63) >= d) incl += t;
    }
    int wid = tid >> 6;
    if ((tid & 63) == 63) wsum[wid] = incl;
    __syncthreads();
    if (tid == 0) {
        int a = 0;
        for (int k = 0; k < 8; ++k) { int t = wsum[k]; wsum[k] = a; a += t; }
    }
    __syncthreads();
    if (tid < nb) boff[tid] = incl - v + wsum[wid];   // exclusive
}

__global__ __launch_bounds__(256) void scan_add(int* __restrict__ rowptr,
                                                const int* __restrict__ boff, int n) {
    int i = blockIdx.x * 256 + threadIdx.x;
    if (i == 0) rowptr[0] = 0;
    if (i < n) rowptr[i + 1] += boff[blockIdx.x];
}

// coarse-bucket cursor init: bucket c region starts at rowptr[64c].
// Counters padded to one per 64B line (stride 16 ints).
__global__ void ccur_init(const int* __restrict__ rowptr, int* __restrict__ ccur) {
    int c = blockIdx.x * blockDim.x + threadIdx.x;
    if (c < NBKT) ccur[c * 16] = rowptr[c * 64];
}

// Pass A: scatter edges to coarse buckets (row>>6). Payload packed 8B:
// x = col | (row&63)<<17, y = weight bits. Active write set = 1563 lines;
// cursors advance sequentially so L2 coalesces 8x 8B writes per 64B line.
// (Cached store is load-bearing here — nt store was an 8.75x write amp.)
__global__ void bucket_scatter(const int* __restrict__ row, const int* __restrict__ col,
                               const float* __restrict__ ew, int* __restrict__ ccur,
                               uint2* __restrict__ tmp) {
    int e = blockIdx.x * blockDim.x + threadIdx.x;
    if (e < N_EDGES) {
        int r = row[e];
        int c = r >> 6;
        int p = atomicAdd(&ccur[c * 16], 1);
        tmp[p] = make_uint2((unsigned)col[e] | ((unsigned)(r & 63) << 17),
                            __float_as_uint(ew[e]));
    }
}

// Pass B: one block per bucket; LDS cursors for the 64 exclusively-owned
// rows; contiguous nt read of bucket region, cached write within 16KB span.
__global__ __launch_bounds__(256) void bucket_sort(const uint2* __restrict__ tmp,
                                                   const int* __restrict__ rowptr,
                                                   int2* __restrict__ colw) {
    __shared__ int lcur[64];
    int c = blockIdx.x;
    int r0 = c * 64;
    int tid = threadIdx.x;
    int rend = r0 + 64; if (rend > N_NODES) rend = N_NODES;
    if (tid < 64) {
        int rr = r0 + tid;
        lcur[tid] = (rr < N_NODES) ? rowptr[rr] : 0;
    }
    __syncthreads();
    int s = rowptr[r0];
    int e = rowptr[rend];
    const u32x2* tp = (const u32x2*)tmp;
    for (int i = s + tid; i < e; i += 256) {
        u32x2 t = __builtin_nontemporal_load(tp + i);
        int rl = (t.x >> 17) & 63;
        int cc = t.x & 0x1FFFF;
        int p = atomicAdd(&lcur[rl], 1);
        colw[p] = make_int2(cc, (int)t.y);
    }
}

// ---------------- propagation ----------------
// One wave per row. 64 lanes = 8 edge-slots x 8 feature-octets.
// Lane (slot=lane>>3, fe=lane&7) handles features [8*fe, 8*fe+7] of edge
// slot: 16B bf16x8 gather per lane, 8 lanes cover a full 128B h-row.
// colw is loaded non-temporally: stream-once per iteration, keep L2 for h.
__global__ __launch_bounds__(256) void prop(const unsigned short* __restrict__ hin,
                                            const int* __restrict__ rowptr,
                                            const int2* __restrict__ colw,
                                            unsigned short* __restrict__ hout,
                                            float* __restrict__ fout, int is_final) {
    int lane = threadIdx.x & 63;
    int r = blockIdx.x * 4 + (threadIdx.x >> 6);
    int fe   = lane & 7;     // feature octet index
    int slot = lane >> 3;    // 0..7

    int s = rowptr[r];
    int e = rowptr[r + 1];
    const unsigned short* hfe = hin + 8 * fe;
    const i32x2* cwp = (const i32x2*)colw;

    float af[8];
    #pragma unroll
    for (int k = 0; k < 8; ++k) af[k] = 0.f;

    int n8 = (e - s) & ~7;
    int i = s;
    #pragma unroll 2
    for (; i < s + n8; i += 8) {
        i32x2 cw = __builtin_nontemporal_load(cwp + i + slot);
        float w = __int_as_float(cw.y);
        bf16x8 p = *(const bf16x8*)(hfe + (unsigned)cw.x * (unsigned)OUT_F);
        #pragma unroll
        for (int k = 0; k < 8; ++k)
            af[k] += w * bf2f((unsigned short)p[k]);
    }
    {   // tail (0..7 edges)
        int ei = i + slot;
        if (ei < e) {
            i32x2 cw = __builtin_nontemporal_load(cwp + ei);
            float w = __int_as_float(cw.y);
            bf16x8 p = *(const bf16x8*)(hfe + (unsigned)cw.x * (unsigned)OUT_F);
            #pragma unroll
            for (int k = 0; k < 8; ++k)
                af[k] += w * bf2f((unsigned short)p[k]);
        }
    }
    // combine the 8 edge-slots
    #pragma unroll
    for (int k = 0; k < 8; ++k) {
        af[k] += __shfl_xor(af[k], 8);
        af[k] += __shfl_xor(af[k], 16);
        af[k] += __shfl_xor(af[k], 32);
    }

    if (slot == 0) {
        bf16x8 ps = *(const bf16x8*)(hin + (unsigned)r * (unsigned)OUT_F + 8 * fe);
        float rr[8];
        #pragma unroll
        for (int k = 0; k < 8; ++k)
            rr[k] = 0.99f * af[k] + 0.01f * bf2f((unsigned short)ps[k]);
        size_t o = (size_t)r * OUT_F + 8 * fe;
        if (is_final) {
            *(float4*)(fout + o)     = make_float4(rr[0], rr[1], rr[2], rr[3]);
            *(float4*)(fout + o + 4) = make_float4(rr[4], rr[5], rr[6], rr[7]);
        } else {
            union { bf16x8 v; unsigned short u[8]; } pk;
            #pragma unroll
            for (int k = 0; k < 8; ++k) pk.u[k] = f2bf(rr[k]);
            *(bf16x8*)(hout + o) = pk.v;
        }
    }
}

extern "C" void kernel_launch(void* const* d_in, const int* in_sizes, int n_in,
                              void* d_out, int out_size, void* d_ws, size_t ws_size,
                              hipStream_t stream) {
    (void)in_sizes; (void)n_in; (void)out_size; (void)ws_size;
    const float* x  = (const float*)d_in[0];
    const float* W1 = (const float*)d_in[1];
    const float* b1 = (const float*)d_in[2];
    const float* W2 = (const float*)d_in[3];
    const float* b2 = (const float*)d_in[4];
    const float* ew = (const float*)d_in[5];
    const int*  row = (const int*)d_in[6];
    const int*  col = (const int*)d_in[7];
    float* out = (float*)d_out;

    char* ws = (char*)d_ws;
    size_t off = 0;
    auto alloc = [&](size_t b) { char* p = ws + off; off += (b + 255) & ~(size_t)255; return p; };
    unsigned short* w1t = (unsigned short*)alloc((size_t)IN_F * HID_F * 2);
    unsigned short* w2t = (unsigned short*)alloc((size_t)HID_F * OUT_F * 2);
    unsigned short* h1  = (unsigned short*)alloc((size_t)N_NODES * HID_F * 2);
    unsigned short* hb0 = (unsigned short*)alloc((size_t)N_NODES * OUT_F * 2);
    unsigned short* hb1 = (unsigned short*)alloc((size_t)N_NODES * OUT_F * 2);
    int*  rowptr = (int*)alloc((size_t)(N_NODES + 1) * 4);
    int*  cnt    = (int*)alloc((size_t)N_NODES * 4);
    int*  bsum   = (int*)alloc(512 * 4);
    int*  boff   = (int*)alloc(512 * 4);
    int*  ccur   = (int*)alloc((size_t)NBKT * 16 * 4);
    uint2* tmp   = (uint2*)alloc((size_t)N_EDGES * 8);
    int2* colw   = (int2*)alloc((size_t)N_EDGES * 8);

    const int NB = (N_NODES + 255) / 256;   // 391

    cast_transpose_w1<<<(IN_F * HID_F + 255) / 256, 256, 0, stream>>>(W1, w1t);
    cast_transpose_w2<<<(HID_F * OUT_F + 255) / 256, 256, 0, stream>>>(W2, w2t);
    gemm1<<<(N_NODES + 63) / 64, 512, 0, stream>>>(x, w1t, b1, h1);
    gemm2<<<(N_NODES + 63) / 64, 256, 0, stream>>>(h1, w2t, b2, hb0);

    hipMemsetAsync(cnt, 0, (size_t)N_NODES * 4, stream);
    count_edges<<<(N_EDGES + 255) / 256, 256, 0, stream>>>(row, cnt);
    scan_local<<<NB, 256, 0, stream>>>(cnt, rowptr, bsum, N_NODES);
    scan_bsum<<<1, 512, 0, stream>>>(bsum, boff, NB);
    scan_add<<<NB, 256, 0, stream>>>(rowptr, boff, N_NODES);
    ccur_init<<<(NBKT + 255) / 256, 256, 0, stream>>>(rowptr, ccur);
    bucket_scatter<<<(N_EDGES + 255) / 256, 256, 0, stream>>>(row, col, ew, ccur, tmp);
    bucket_sort<<<NBKT, 256, 0, stream>>>(tmp, rowptr, colw);

    const unsigned short* pin = hb0;
    for (int s = 0; s < 10; ++s) {
        int last = (s == 9);
        unsigned short* pout = (s & 1) ? hb0 : hb1;
        prop<<<N_NODES / 4, 256, 0, stream>>>(pin, rowptr, colw, pout, out, last);
        pin = pout;
    }
}

// Round 4
// 1534.351 us; speedup vs baseline: 1.0804x; 1.0326x over previous
//
#include <hip/hip_runtime.h>

// APPNP: h0 = relu(x@W1+b1)@W2+b2 ; 10x h = 0.99*SpMM(h) + 0.01*h
// bf16 MFMA GEMMs, on-device CSR build, gather SpMM with bf16 h storage.
// R4: two-phase bucket sort; LDS cursors in pass B; 32-bit gather index.
// R6 post-mortem: nt stores = 8.75x write amp (224 MB). REVERTED.
// R7 post-mortem: write amp persists WITHOUT nt (181 MB = 7x): a bucket's
//     tmp lines are written from all 8 XCDs concurrently; per-XCD L2s are
//     non-coherent so each holds a partial dirty line -> ~full-line
//     writeback per 8B store. Also gemm1 is latency-bound (MfmaUtil 4%,
//     VALUBusy 10%, 702 GB/s): dependent fp32-load + 16x f2bf chain per
//     kk. And nt loads killed LLC reuse of colw (read 10x) -> reverted.
// R8: (a) XCD-partitioned scatter: each coarse bucket split into 8
//     part-segments by blockIdx%8 (round-robin XCD heuristic) so every
//     tmp line is written by one XCD only; per-(part,bucket) counts fused
//     into count_edges (identical grid => identical part mapping).
//     (b) x pre-cast to bf16 (xb aliases tmp/colw region, disjoint
//     lifetimes); gemm1 reads 16B bf16x8 directly, no convert ALU.
//     (c) all nontemporal hints removed.

#define N_NODES 100000
#define N_EDGES 3200000
#define IN_F    512
#define HID_F   256
#define OUT_F   64
#define NBKT    ((N_NODES + 63) / 64)   // 1563 coarse buckets (row>>6)

typedef short bf16x8 __attribute__((ext_vector_type(8)));
typedef float f32x4  __attribute__((ext_vector_type(4)));

__device__ __forceinline__ unsigned short f2bf(float f) {
    unsigned int u = __float_as_uint(f);
    unsigned int r = (u + 0x7FFFu + ((u >> 16) & 1u)) >> 16;  // RNE
    return (unsigned short)r;
}
__device__ __forceinline__ float bf2f(unsigned short h) {
    return __uint_as_float(((unsigned int)h) << 16);
}

// ---------------- weight cast+transpose ----------------
__global__ void cast_transpose_w1(const float* __restrict__ w, unsigned short* __restrict__ wt) {
    int idx = blockIdx.x * blockDim.x + threadIdx.x;   // over 512*256
    if (idx >= IN_F * HID_F) return;
    int k = idx / HID_F, n = idx % HID_F;
    wt[(size_t)n * IN_F + k] = f2bf(w[idx]);           // W1T [HID_F][IN_F]
}
__global__ void cast_transpose_w2(const float* __restrict__ w, unsigned short* __restrict__ wt) {
    int idx = blockIdx.x * blockDim.x + threadIdx.x;   // over 256*64
    if (idx >= HID_F * OUT_F) return;
    int k = idx / OUT_F, n = idx % OUT_F;
    wt[(size_t)n * HID_F + k] = f2bf(w[idx]);          // W2T [OUT_F][HID_F]
}

// ---------------- x cast: fp32 -> bf16, coalesced stream ----------------
__global__ __launch_bounds__(256) void cast_x(const float* __restrict__ x,
                                              unsigned short* __restrict__ xb) {
    int idx = blockIdx.x * 256 + threadIdx.x;          // octet index, 6.4M total
    if (idx >= N_NODES * IN_F / 8) return;
    const float4* s = (const float4*)(x + (size_t)idx * 8);
    float4 f0 = s[0], f1 = s[1];
    union { bf16x8 v; unsigned short u[8]; } t;
    t.u[0] = f2bf(f0.x); t.u[1] = f2bf(f0.y); t.u[2] = f2bf(f0.z); t.u[3] = f2bf(f0.w);
    t.u[4] = f2bf(f1.x); t.u[5] = f2bf(f1.y); t.u[6] = f2bf(f1.z); t.u[7] = f2bf(f1.w);
    *(bf16x8*)(xb + (size_t)idx * 8) = t.v;
}

// ---------------- GEMM1: h1 = relu(xb @ W1 + b1), bf16 in/out ----------------
__global__ __launch_bounds__(512) void gemm1(const unsigned short* __restrict__ xb,
                                             const unsigned short* __restrict__ w1t,
                                             const float* __restrict__ b1,
                                             unsigned short* __restrict__ h1) {
    int tid  = threadIdx.x;
    int lane = tid & 63;
    int w    = tid >> 6;     // 0..7
    int wm   = w >> 2;       // 0..1
    int wn   = w & 3;        // 0..3
    int quad = lane >> 4;    // 0..3
    int lm   = lane & 15;
    int m0 = blockIdx.x * 64 + wm * 32;
    int n0 = wn * 64;

    f32x4 acc[2][4];
    for (int i = 0; i < 2; ++i)
        for (int j = 0; j < 4; ++j)
            acc[i][j] = (f32x4){0.f, 0.f, 0.f, 0.f};

    for (int kk = 0; kk < IN_F; kk += 32) {
        bf16x8 a[2], b[4];
        for (int i = 0; i < 2; ++i) {
            int m = m0 + i * 16 + lm;
            if (m > N_NODES - 1) m = N_NODES - 1;            // clamp loads, mask stores
            a[i] = *(const bf16x8*)(xb + (size_t)m * IN_F + kk + quad * 8);
        }
        for (int j = 0; j < 4; ++j) {
            int n = n0 + j * 16 + lm;
            b[j] = *(const bf16x8*)(w1t + (size_t)n * IN_F + kk + quad * 8);
        }
        for (int i = 0; i < 2; ++i)
            for (int j = 0; j < 4; ++j)
                acc[i][j] = __builtin_amdgcn_mfma_f32_16x16x32_bf16(a[i], b[j], acc[i][j], 0, 0, 0);
    }

    for (int i = 0; i < 2; ++i)
        for (int j = 0; j < 4; ++j) {
            int n = n0 + j * 16 + lm;
            float bias = b1[n];
            for (int r = 0; r < 4; ++r) {
                int m = m0 + i * 16 + quad * 4 + r;   // C/D: row=(lane>>4)*4+reg, col=lane&15
                if (m < N_NODES) {
                    float v = acc[i][j][r] + bias;
                    v = v > 0.f ? v : 0.f;
                    h1[(size_t)m * HID_F + n] = f2bf(v);
                }
            }
        }
}

// ---------------- GEMM2: h0 = h1 @ W2 + b2, bf16 out ----------------
__global__ __launch_bounds__(256) void gemm2(const unsigned short* __restrict__ h1,
                                             const unsigned short* __restrict__ w2t,
                                             const float* __restrict__ b2,
                                             unsigned short* __restrict__ h0) {
    int tid  = threadIdx.x;
    int lane = tid & 63;
    int w    = tid >> 6;     // 0..3
    int wm   = w >> 1;       // 0..1
    int wn   = w & 1;        // 0..1
    int quad = lane >> 4;
    int lm   = lane & 15;
    int m0 = blockIdx.x * 64 + wm * 32;
    int n0 = wn * 32;

    f32x4 acc[2][2];
    for (int i = 0; i < 2; ++i)
        for (int j = 0; j < 2; ++j)
            acc[i][j] = (f32x4){0.f, 0.f, 0.f, 0.f};

    for (int kk = 0; kk < HID_F; kk += 32) {
        bf16x8 a[2], b[2];
        for (int i = 0; i < 2; ++i) {
            int m = m0 + i * 16 + lm;
            if (m > N_NODES - 1) m = N_NODES - 1;
            a[i] = *(const bf16x8*)(h1 + (size_t)m * HID_F + kk + quad * 8);
        }
        for (int j = 0; j < 2; ++j) {
            int n = n0 + j * 16 + lm;
            b[j] = *(const bf16x8*)(w2t + (size_t)n * HID_F + kk + quad * 8);
        }
        for (int i = 0; i < 2; ++i)
            for (int j = 0; j < 2; ++j)
                acc[i][j] = __builtin_amdgcn_mfma_f32_16x16x32_bf16(a[i], b[j], acc[i][j], 0, 0, 0);
    }

    for (int i = 0; i < 2; ++i)
        for (int j = 0; j < 2; ++j) {
            int n = n0 + j * 16 + lm;
            float bias = b2[n];
            for (int r = 0; r < 4; ++r) {
                int m = m0 + i * 16 + quad * 4 + r;
                if (m < N_NODES) {
                    float v = acc[i][j][r] + bias;
                    h0[(size_t)m * OUT_F + n] = f2bf(v);
                }
            }
        }
}

// ---------------- CSR build ----------------
// Per-row counts for rowptr AND per-(part,bucket) counts for the
// XCD-partitioned scatter. part = blockIdx&7 — grid MUST match
// bucket_scatter's grid exactly so the mapping is identical.
__global__ void count_edges(const int* __restrict__ row, int* __restrict__ cnt,
                            int* __restrict__ pcnt) {
    int e = blockIdx.x * blockDim.x + threadIdx.x;
    if (e < N_EDGES) {
        int r = row[e];
        atomicAdd(&cnt[r], 1);
        atomicAdd(&pcnt[(blockIdx.x & 7) * NBKT + (r >> 6)], 1);
    }
}

// hierarchical scan: rowptr[i+1] = inclusive-prefix(cnt[0..i]), rowptr[0]=0
__global__ __launch_bounds__(256) void scan_local(const int* __restrict__ cnt,
                                                  int* __restrict__ rowptr,
                                                  int* __restrict__ bsum, int n) {
    __shared__ int wsum[4];
    int tid = threadIdx.x;
    int i = blockIdx.x * 256 + tid;
    int v = (i < n) ? cnt[i] : 0;
    int incl = v;
    for (int d = 1; d < 64; d <<= 1) {
        int t = __shfl_up(incl, d);
        if ((tid & 63) >= d) incl += t;
    }
    int wid = tid >> 6;
    if ((tid & 63) == 63) wsum[wid] = incl;
    __syncthreads();
    if (tid == 0) {
        int a = 0;
        for (int k = 0; k < 4; ++k) { int t = wsum[k]; wsum[k] = a; a += t; }
        bsum[blockIdx.x] = a;
    }
    __syncthreads();
    if (i < n) rowptr[i + 1] = incl + wsum[wid];   // block offset added later
}

__global__ __launch_bounds__(512) void scan_bsum(const int* __restrict__ bsum,
                                                 int* __restrict__ boff, int nb) {
    __shared__ int wsum[8];
    int tid = threadIdx.x;
    int v = (tid < nb) ? bsum[tid] : 0;
    int incl = v;
    for (int d = 1; d < 64; d <<= 1) {
        int t = __shfl_up(incl, d);
        if ((tid & 63) >= d) incl += t;
    }
    int wid = tid >> 6;
    if ((tid & 63) == 63) wsum[wid] = incl;
    __syncthreads();
    if (tid == 0) {
        int a = 0;
        for (int k = 0; k < 8; ++k) { int t = wsum[k]; wsum[k] = a; a += t; }
    }
    __syncthreads();
    if (tid < nb) boff[tid] = incl - v + wsum[wid];   // exclusive
}

__global__ __launch_bounds__(256) void scan_add(int* __restrict__ rowptr,
                                                const int* __restrict__ boff, int n) {
    int i = blockIdx.x * 256 + threadIdx.x;
    if (i == 0) rowptr[0] = 0;
    if (i < n) rowptr[i + 1] += boff[blockIdx.x];
}

// Per-(part,bucket) cursor init: bucket c region [rowptr[64c], ...) is
// subdivided into 8 part segments sized by pcnt. Pass B is order-agnostic
// within the bucket, so the subdivision is invisible downstream.
__global__ void pcur_init(const int* __restrict__ rowptr, const int* __restrict__ pcnt,
                          int* __restrict__ pcur) {
    int c = blockIdx.x * blockDim.x + threadIdx.x;
    if (c < NBKT) {
        int base = rowptr[c * 64];
        for (int p = 0; p < 8; ++p) {
            pcur[p * NBKT + c] = base;
            base += pcnt[p * NBKT + c];
        }
    }
}

// Pass A: scatter edges to coarse buckets (row>>6), XCD-partitioned.
// All writes to segment (c, p) come only from blocks with blockIdx%8==p,
// which the round-robin dispatch places on one XCD -> its L2 owns each
// 64B line exclusively and coalesces the 8x 8B writes (kills the 7x
// cross-XCD partial-line write amplification measured in R7).
__global__ void bucket_scatter(const int* __restrict__ row, const int* __restrict__ col,
                               const float* __restrict__ ew, int* __restrict__ pcur,
                               uint2* __restrict__ tmp) {
    int e = blockIdx.x * blockDim.x + threadIdx.x;
    int part = (blockIdx.x & 7) * NBKT;
    if (e < N_EDGES) {
        int r = row[e];
        int c = r >> 6;
        int p = atomicAdd(&pcur[part + c], 1);
        tmp[p] = make_uint2((unsigned)col[e] | ((unsigned)(r & 63) << 17),
                            __float_as_uint(ew[e]));
    }
}

// Pass B: one block per bucket; LDS cursors for the 64 exclusively-owned
// rows; contiguous read of bucket region, write within 16KB span.
__global__ __launch_bounds__(256) void bucket_sort(const uint2* __restrict__ tmp,
                                                   const int* __restrict__ rowptr,
                                                   int2* __restrict__ colw) {
    __shared__ int lcur[64];
    int c = blockIdx.x;
    int r0 = c * 64;
    int tid = threadIdx.x;
    int rend = r0 + 64; if (rend > N_NODES) rend = N_NODES;
    if (tid < 64) {
        int rr = r0 + tid;
        lcur[tid] = (rr < N_NODES) ? rowptr[rr] : 0;
    }
    __syncthreads();
    int s = rowptr[r0];
    int e = rowptr[rend];
    for (int i = s + tid; i < e; i += 256) {
        uint2 t = tmp[i];
        int rl = (t.x >> 17) & 63;
        int cc = t.x & 0x1FFFF;
        int p = atomicAdd(&lcur[rl], 1);
        colw[p] = make_int2(cc, (int)t.y);
    }
}

// ---------------- propagation ----------------
// One wave per row. 64 lanes = 8 edge-slots x 8 feature-octets.
// Lane (slot=lane>>3, fe=lane&7) handles features [8*fe, 8*fe+7] of edge
// slot: 16B bf16x8 gather per lane, 8 lanes cover a full 128B h-row.
__global__ __launch_bounds__(256) void prop(const unsigned short* __restrict__ hin,
                                            const int* __restrict__ rowptr,
                                            const int2* __restrict__ colw,
                                            unsigned short* __restrict__ hout,
                                            float* __restrict__ fout, int is_final) {
    int lane = threadIdx.x & 63;
    int r = blockIdx.x * 4 + (threadIdx.x >> 6);
    int fe   = lane & 7;     // feature octet index
    int slot = lane >> 3;    // 0..7

    int s = rowptr[r];
    int e = rowptr[r + 1];
    const unsigned short* hfe = hin + 8 * fe;

    float af[8];
    #pragma unroll
    for (int k = 0; k < 8; ++k) af[k] = 0.f;

    int n8 = (e - s) & ~7;
    int i = s;
    #pragma unroll 2
    for (; i < s + n8; i += 8) {
        int2 cw = colw[i + slot];
        float w = __int_as_float(cw.y);
        bf16x8 p = *(const bf16x8*)(hfe + (unsigned)cw.x * (unsigned)OUT_F);
        #pragma unroll
        for (int k = 0; k < 8; ++k)
            af[k] += w * bf2f((unsigned short)p[k]);
    }
    {   // tail (0..7 edges)
        int ei = i + slot;
        if (ei < e) {
            int2 cw = colw[ei];
            float w = __int_as_float(cw.y);
            bf16x8 p = *(const bf16x8*)(hfe + (unsigned)cw.x * (unsigned)OUT_F);
            #pragma unroll
            for (int k = 0; k < 8; ++k)
                af[k] += w * bf2f((unsigned short)p[k]);
        }
    }
    // combine the 8 edge-slots
    #pragma unroll
    for (int k = 0; k < 8; ++k) {
        af[k] += __shfl_xor(af[k], 8);
        af[k] += __shfl_xor(af[k], 16);
        af[k] += __shfl_xor(af[k], 32);
    }

    if (slot == 0) {
        bf16x8 ps = *(const bf16x8*)(hin + (unsigned)r * (unsigned)OUT_F + 8 * fe);
        float rr[8];
        #pragma unroll
        for (int k = 0; k < 8; ++k)
            rr[k] = 0.99f * af[k] + 0.01f * bf2f((unsigned short)ps[k]);
        size_t o = (size_t)r * OUT_F + 8 * fe;
        if (is_final) {
            *(float4*)(fout + o)     = make_float4(rr[0], rr[1], rr[2], rr[3]);
            *(float4*)(fout + o + 4) = make_float4(rr[4], rr[5], rr[6], rr[7]);
        } else {
            union { bf16x8 v; unsigned short u[8]; } pk;
            #pragma unroll
            for (int k = 0; k < 8; ++k) pk.u[k] = f2bf(rr[k]);
            *(bf16x8*)(hout + o) = pk.v;
        }
    }
}

extern "C" void kernel_launch(void* const* d_in, const int* in_sizes, int n_in,
                              void* d_out, int out_size, void* d_ws, size_t ws_size,
                              hipStream_t stream) {
    (void)in_sizes; (void)n_in; (void)out_size; (void)ws_size;
    const float* x  = (const float*)d_in[0];
    const float* W1 = (const float*)d_in[1];
    const float* b1 = (const float*)d_in[2];
    const float* W2 = (const float*)d_in[3];
    const float* b2 = (const float*)d_in[4];
    const float* ew = (const float*)d_in[5];
    const int*  row = (const int*)d_in[6];
    const int*  col = (const int*)d_in[7];
    float* out = (float*)d_out;

    char* ws = (char*)d_ws;
    size_t off = 0;
    auto alloc = [&](size_t b) { char* p = ws + off; off += (b + 255) & ~(size_t)255; return p; };
    // Region A: xb (102.4MB, lifetime cast_x..gemm1) aliases
    // tmp (25.6MB) + colw (25.6MB) (lifetime bucket_scatter..end).
    char* regionA = alloc((size_t)N_NODES * IN_F * 2);
    unsigned short* xb  = (unsigned short*)regionA;
    uint2* tmp  = (uint2*)regionA;
    int2*  colw = (int2*)(regionA + (size_t)N_EDGES * 8);
    unsigned short* w1t = (unsigned short*)alloc((size_t)IN_F * HID_F * 2);
    unsigned short* w2t = (unsigned short*)alloc((size_t)HID_F * OUT_F * 2);
    unsigned short* h1  = (unsigned short*)alloc((size_t)N_NODES * HID_F * 2);
    unsigned short* hb0 = (unsigned short*)alloc((size_t)N_NODES * OUT_F * 2);
    unsigned short* hb1 = (unsigned short*)alloc((size_t)N_NODES * OUT_F * 2);
    int*  rowptr = (int*)alloc((size_t)(N_NODES + 1) * 4);
    int*  cnt    = (int*)alloc((size_t)N_NODES * 4);
    int*  bsum   = (int*)alloc(512 * 4);
    int*  boff   = (int*)alloc(512 * 4);
    int*  pcnt   = (int*)alloc((size_t)8 * NBKT * 4);
    int*  pcur   = (int*)alloc((size_t)8 * NBKT * 4);

    const int NB = (N_NODES + 255) / 256;   // 391
    const int EB = (N_EDGES + 255) / 256;   // 12500 — shared by count & scatter

    cast_transpose_w1<<<(IN_F * HID_F + 255) / 256, 256, 0, stream>>>(W1, w1t);
    cast_transpose_w2<<<(HID_F * OUT_F + 255) / 256, 256, 0, stream>>>(W2, w2t);
    cast_x<<<(N_NODES * IN_F / 8 + 255) / 256, 256, 0, stream>>>(x, xb);
    gemm1<<<(N_NODES + 63) / 64, 512, 0, stream>>>(xb, w1t, b1, h1);
    gemm2<<<(N_NODES + 63) / 64, 256, 0, stream>>>(h1, w2t, b2, hb0);

    hipMemsetAsync(cnt, 0, (size_t)N_NODES * 4, stream);
    hipMemsetAsync(pcnt, 0, (size_t)8 * NBKT * 4, stream);
    count_edges<<<EB, 256, 0, stream>>>(row, cnt, pcnt);
    scan_local<<<NB, 256, 0, stream>>>(cnt, rowptr, bsum, N_NODES);
    scan_bsum<<<1, 512, 0, stream>>>(bsum, boff, NB);
    scan_add<<<NB, 256, 0, stream>>>(rowptr, boff, N_NODES);
    pcur_init<<<(NBKT + 255) / 256, 256, 0, stream>>>(rowptr, pcnt, pcur);
    bucket_scatter<<<EB, 256, 0, stream>>>(row, col, ew, pcur, tmp);
    bucket_sort<<<NBKT, 256, 0, stream>>>(tmp, rowptr, colw);

    const unsigned short* pin = hb0;
    for (int s = 0; s < 10; ++s) {
        int last = (s == 9);
        unsigned short* pout = (s & 1) ? hb0 : hb1;
        prop<<<N_NODES / 4, 256, 0, stream>>>(pin, rowptr, colw, pout, out, last);
        pin = pout;
    }
}

// Round 5
// 1492.504 us; speedup vs baseline: 1.1107x; 1.0280x over previous
//
#include <hip/hip_runtime.h>

// APPNP: h0 = relu(x@W1+b1)@W2+b2 ; 10x h = 0.99*SpMM(h) + 0.01*h
// bf16 MFMA GEMMs, on-device CSR build, gather SpMM with bf16 h storage.
// R4: two-phase bucket sort; LDS cursors in pass B; 32-bit gather index.
// R6/R7 post-mortems: cross-XCD writes to shared lines cause ~full-line
//     writeback per 8B store (per-XCD L2s non-coherent). nt hints all bad.
// R8: XCD-partitioned scatter (blockIdx%8 part-segments) fixed
//     bucket_scatter (out of top-5); bf16 pre-cast fixed gemm1 input path.
// R8 post-mortem: count_edges was ALWAYS ~239us with 187MB WRITE_SIZE —
//     same cross-XCD pathology on the ATOMIC path: cnt[] lines ping-pong
//     between 8 non-coherent L2s, each migration = dirty-line writeback.
//     (R8's pcnt atomic, already partitioned by blockIdx&7, cost ~0 —
//     confirms partitioned atomics are L2-local and cheap.)
// R9: cnt -> cnt8[part][row], part=blockIdx&7: every counter line owned
//     by one XCD; scan_local sums the 8 parts per row.

#define N_NODES 100000
#define N_EDGES 3200000
#define IN_F    512
#define HID_F   256
#define OUT_F   64
#define NBKT    ((N_NODES + 63) / 64)   // 1563 coarse buckets (row>>6)

typedef short bf16x8 __attribute__((ext_vector_type(8)));
typedef float f32x4  __attribute__((ext_vector_type(4)));

__device__ __forceinline__ unsigned short f2bf(float f) {
    unsigned int u = __float_as_uint(f);
    unsigned int r = (u + 0x7FFFu + ((u >> 16) & 1u)) >> 16;  // RNE
    return (unsigned short)r;
}
__device__ __forceinline__ float bf2f(unsigned short h) {
    return __uint_as_float(((unsigned int)h) << 16);
}

// ---------------- weight cast+transpose ----------------
__global__ void cast_transpose_w1(const float* __restrict__ w, unsigned short* __restrict__ wt) {
    int idx = blockIdx.x * blockDim.x + threadIdx.x;   // over 512*256
    if (idx >= IN_F * HID_F) return;
    int k = idx / HID_F, n = idx % HID_F;
    wt[(size_t)n * IN_F + k] = f2bf(w[idx]);           // W1T [HID_F][IN_F]
}
__global__ void cast_transpose_w2(const float* __restrict__ w, unsigned short* __restrict__ wt) {
    int idx = blockIdx.x * blockDim.x + threadIdx.x;   // over 256*64
    if (idx >= HID_F * OUT_F) return;
    int k = idx / OUT_F, n = idx % OUT_F;
    wt[(size_t)n * HID_F + k] = f2bf(w[idx]);          // W2T [OUT_F][HID_F]
}

// ---------------- x cast: fp32 -> bf16, coalesced stream ----------------
__global__ __launch_bounds__(256) void cast_x(const float* __restrict__ x,
                                              unsigned short* __restrict__ xb) {
    int idx = blockIdx.x * 256 + threadIdx.x;          // octet index, 6.4M total
    if (idx >= N_NODES * IN_F / 8) return;
    const float4* s = (const float4*)(x + (size_t)idx * 8);
    float4 f0 = s[0], f1 = s[1];
    union { bf16x8 v; unsigned short u[8]; } t;
    t.u[0] = f2bf(f0.x); t.u[1] = f2bf(f0.y); t.u[2] = f2bf(f0.z); t.u[3] = f2bf(f0.w);
    t.u[4] = f2bf(f1.x); t.u[5] = f2bf(f1.y); t.u[6] = f2bf(f1.z); t.u[7] = f2bf(f1.w);
    *(bf16x8*)(xb + (size_t)idx * 8) = t.v;
}

// ---------------- GEMM1: h1 = relu(xb @ W1 + b1), bf16 in/out ----------------
__global__ __launch_bounds__(512) void gemm1(const unsigned short* __restrict__ xb,
                                             const unsigned short* __restrict__ w1t,
                                             const float* __restrict__ b1,
                                             unsigned short* __restrict__ h1) {
    int tid  = threadIdx.x;
    int lane = tid & 63;
    int w    = tid >> 6;     // 0..7
    int wm   = w >> 2;       // 0..1
    int wn   = w & 3;        // 0..3
    int quad = lane >> 4;    // 0..3
    int lm   = lane & 15;
    int m0 = blockIdx.x * 64 + wm * 32;
    int n0 = wn * 64;

    f32x4 acc[2][4];
    for (int i = 0; i < 2; ++i)
        for (int j = 0; j < 4; ++j)
            acc[i][j] = (f32x4){0.f, 0.f, 0.f, 0.f};

    for (int kk = 0; kk < IN_F; kk += 32) {
        bf16x8 a[2], b[4];
        for (int i = 0; i < 2; ++i) {
            int m = m0 + i * 16 + lm;
            if (m > N_NODES - 1) m = N_NODES - 1;            // clamp loads, mask stores
            a[i] = *(const bf16x8*)(xb + (size_t)m * IN_F + kk + quad * 8);
        }
        for (int j = 0; j < 4; ++j) {
            int n = n0 + j * 16 + lm;
            b[j] = *(const bf16x8*)(w1t + (size_t)n * IN_F + kk + quad * 8);
        }
        for (int i = 0; i < 2; ++i)
            for (int j = 0; j < 4; ++j)
                acc[i][j] = __builtin_amdgcn_mfma_f32_16x16x32_bf16(a[i], b[j], acc[i][j], 0, 0, 0);
    }

    for (int i = 0; i < 2; ++i)
        for (int j = 0; j < 4; ++j) {
            int n = n0 + j * 16 + lm;
            float bias = b1[n];
            for (int r = 0; r < 4; ++r) {
                int m = m0 + i * 16 + quad * 4 + r;   // C/D: row=(lane>>4)*4+reg, col=lane&15
                if (m < N_NODES) {
                    float v = acc[i][j][r] + bias;
                    v = v > 0.f ? v : 0.f;
                    h1[(size_t)m * HID_F + n] = f2bf(v);
                }
            }
        }
}

// ---------------- GEMM2: h0 = h1 @ W2 + b2, bf16 out ----------------
__global__ __launch_bounds__(256) void gemm2(const unsigned short* __restrict__ h1,
                                             const unsigned short* __restrict__ w2t,
                                             const float* __restrict__ b2,
                                             unsigned short* __restrict__ h0) {
    int tid  = threadIdx.x;
    int lane = tid & 63;
    int w    = tid >> 6;     // 0..3
    int wm   = w >> 1;       // 0..1
    int wn   = w & 1;        // 0..1
    int quad = lane >> 4;
    int lm   = lane & 15;
    int m0 = blockIdx.x * 64 + wm * 32;
    int n0 = wn * 32;

    f32x4 acc[2][2];
    for (int i = 0; i < 2; ++i)
        for (int j = 0; j < 2; ++j)
            acc[i][j] = (f32x4){0.f, 0.f, 0.f, 0.f};

    for (int kk = 0; kk < HID_F; kk += 32) {
        bf16x8 a[2], b[2];
        for (int i = 0; i < 2; ++i) {
            int m = m0 + i * 16 + lm;
            if (m > N_NODES - 1) m = N_NODES - 1;
            a[i] = *(const bf16x8*)(h1 + (size_t)m * HID_F + kk + quad * 8);
        }
        for (int j = 0; j < 2; ++j) {
            int n = n0 + j * 16 + lm;
            b[j] = *(const bf16x8*)(w2t + (size_t)n * HID_F + kk + quad * 8);
        }
        for (int i = 0; i < 2; ++i)
            for (int j = 0; j < 2; ++j)
                acc[i][j] = __builtin_amdgcn_mfma_f32_16x16x32_bf16(a[i], b[j], acc[i][j], 0, 0, 0);
    }

    for (int i = 0; i < 2; ++i)
        for (int j = 0; j < 2; ++j) {
            int n = n0 + j * 16 + lm;
            float bias = b2[n];
            for (int r = 0; r < 4; ++r) {
                int m = m0 + i * 16 + quad * 4 + r;
                if (m < N_NODES) {
                    float v = acc[i][j][r] + bias;
                    h0[(size_t)m * OUT_F + n] = f2bf(v);
                }
            }
        }
}

// ---------------- CSR build ----------------
// XCD-partitioned counts: part = blockIdx&7 (round-robin XCD heuristic;
// grid MUST match bucket_scatter's). cnt8[part][row] and pcnt[part][bkt]
// are each touched by one XCD only -> atomics stay L2-local, no
// cross-XCD line ping-pong (R8 post-mortem: shared cnt[] = 187MB HBM
// writes from ownership-migration writebacks).
__global__ void count_edges(const int* __restrict__ row, int* __restrict__ cnt8,
                            int* __restrict__ pcnt) {
    int e = blockIdx.x * blockDim.x + threadIdx.x;
    int part = blockIdx.x & 7;
    if (e < N_EDGES) {
        int r = row[e];
        atomicAdd(&cnt8[part * N_NODES + r], 1);
        atomicAdd(&pcnt[part * NBKT + (r >> 6)], 1);
    }
}

// hierarchical scan: rowptr[i+1] = inclusive-prefix(cnt[0..i]), rowptr[0]=0
// cnt[i] = sum over the 8 XCD partitions.
__global__ __launch_bounds__(256) void scan_local(const int* __restrict__ cnt8,
                                                  int* __restrict__ rowptr,
                                                  int* __restrict__ bsum, int n) {
    __shared__ int wsum[4];
    int tid = threadIdx.x;
    int i = blockIdx.x * 256 + tid;
    int v = 0;
    if (i < n) {
        #pragma unroll
        for (int p = 0; p < 8; ++p)
            v += cnt8[(size_t)p * N_NODES + i];
    }
    int incl = v;
    for (int d = 1; d < 64; d <<= 1) {
        int t = __shfl_up(incl, d);
        if ((tid & 63) >= d) incl += t;
    }
    int wid = tid >> 6;
    if ((tid & 63) == 63) wsum[wid] = incl;
    __syncthreads();
    if (tid == 0) {
        int a = 0;
        for (int k = 0; k < 4; ++k) { int t = wsum[k]; wsum[k] = a; a += t; }
        bsum[blockIdx.x] = a;
    }
    __syncthreads();
    if (i < n) rowptr[i + 1] = incl + wsum[wid];   // block offset added later
}

__global__ __launch_bounds__(512) void scan_bsum(const int* __restrict__ bsum,
                                                 int* __restrict__ boff, int nb) {
    __shared__ int wsum[8];
    int tid = threadIdx.x;
    int v = (tid < nb) ? bsum[tid] : 0;
    int incl = v;
    for (int d = 1; d < 64; d <<= 1) {
        int t = __shfl_up(incl, d);
        if ((tid & 63) >= d) incl += t;
    }
    int wid = tid >> 6;
    if ((tid & 63) == 63) wsum[wid] = incl;
    __syncthreads();
    if (tid == 0) {
        int a = 0;
        for (int k = 0; k < 8; ++k) { int t = wsum[k]; wsum[k] = a; a += t; }
    }
    __syncthreads();
    if (tid < nb) boff[tid] = incl - v + wsum[wid];   // exclusive
}

__global__ __launch_bounds__(256) void scan_add(int* __restrict__ rowptr,
                                                const int* __restrict__ boff, int n) {
    int i = blockIdx.x * 256 + threadIdx.x;
    if (i == 0) rowptr[0] = 0;
    if (i < n) rowptr[i + 1] += boff[blockIdx.x];
}

// Per-(part,bucket) cursor init: bucket c region [rowptr[64c], ...) is
// subdivided into 8 part segments sized by pcnt. Pass B is order-agnostic
// within the bucket, so the subdivision is invisible downstream.
__global__ void pcur_init(const int* __restrict__ rowptr, const int* __restrict__ pcnt,
                          int* __restrict__ pcur) {
    int c = blockIdx.x * blockDim.x + threadIdx.x;
    if (c < NBKT) {
        int base = rowptr[c * 64];
        for (int p = 0; p < 8; ++p) {
            pcur[p * NBKT + c] = base;
            base += pcnt[p * NBKT + c];
        }
    }
}

// Pass A: scatter edges to coarse buckets (row>>6), XCD-partitioned.
// All writes to segment (c, p) come only from blocks with blockIdx%8==p,
// which the round-robin dispatch places on one XCD -> its L2 owns each
// 64B line exclusively and coalesces the 8x 8B writes.
__global__ void bucket_scatter(const int* __restrict__ row, const int* __restrict__ col,
                               const float* __restrict__ ew, int* __restrict__ pcur,
                               uint2* __restrict__ tmp) {
    int e = blockIdx.x * blockDim.x + threadIdx.x;
    int part = (blockIdx.x & 7) * NBKT;
    if (e < N_EDGES) {
        int r = row[e];
        int c = r >> 6;
        int p = atomicAdd(&pcur[part + c], 1);
        tmp[p] = make_uint2((unsigned)col[e] | ((unsigned)(r & 63) << 17),
                            __float_as_uint(ew[e]));
    }
}

// Pass B: one block per bucket; LDS cursors for the 64 exclusively-owned
// rows; contiguous read of bucket region, write within 16KB span.
__global__ __launch_bounds__(256) void bucket_sort(const uint2* __restrict__ tmp,
                                                   const int* __restrict__ rowptr,
                                                   int2* __restrict__ colw) {
    __shared__ int lcur[64];
    int c = blockIdx.x;
    int r0 = c * 64;
    int tid = threadIdx.x;
    int rend = r0 + 64; if (rend > N_NODES) rend = N_NODES;
    if (tid < 64) {
        int rr = r0 + tid;
        lcur[tid] = (rr < N_NODES) ? rowptr[rr] : 0;
    }
    __syncthreads();
    int s = rowptr[r0];
    int e = rowptr[rend];
    for (int i = s + tid; i < e; i += 256) {
        uint2 t = tmp[i];
        int rl = (t.x >> 17) & 63;
        int cc = t.x & 0x1FFFF;
        int p = atomicAdd(&lcur[rl], 1);
        colw[p] = make_int2(cc, (int)t.y);
    }
}

// ---------------- propagation ----------------
// One wave per row. 64 lanes = 8 edge-slots x 8 feature-octets.
// Lane (slot=lane>>3, fe=lane&7) handles features [8*fe, 8*fe+7] of edge
// slot: 16B bf16x8 gather per lane, 8 lanes cover a full 128B h-row.
__global__ __launch_bounds__(256) void prop(const unsigned short* __restrict__ hin,
                                            const int* __restrict__ rowptr,
                                            const int2* __restrict__ colw,
                                            unsigned short* __restrict__ hout,
                                            float* __restrict__ fout, int is_final) {
    int lane = threadIdx.x & 63;
    int r = blockIdx.x * 4 + (threadIdx.x >> 6);
    int fe   = lane & 7;     // feature octet index
    int slot = lane >> 3;    // 0..7

    int s = rowptr[r];
    int e = rowptr[r + 1];
    const unsigned short* hfe = hin + 8 * fe;

    float af[8];
    #pragma unroll
    for (int k = 0; k < 8; ++k) af[k] = 0.f;

    int n8 = (e - s) & ~7;
    int i = s;
    #pragma unroll 2
    for (; i < s + n8; i += 8) {
        int2 cw = colw[i + slot];
        float w = __int_as_float(cw.y);
        bf16x8 p = *(const bf16x8*)(hfe + (unsigned)cw.x * (unsigned)OUT_F);
        #pragma unroll
        for (int k = 0; k < 8; ++k)
            af[k] += w * bf2f((unsigned short)p[k]);
    }
    {   // tail (0..7 edges)
        int ei = i + slot;
        if (ei < e) {
            int2 cw = colw[ei];
            float w = __int_as_float(cw.y);
            bf16x8 p = *(const bf16x8*)(hfe + (unsigned)cw.x * (unsigned)OUT_F);
            #pragma unroll
            for (int k = 0; k < 8; ++k)
                af[k] += w * bf2f((unsigned short)p[k]);
        }
    }
    // combine the 8 edge-slots
    #pragma unroll
    for (int k = 0; k < 8; ++k) {
        af[k] += __shfl_xor(af[k], 8);
        af[k] += __shfl_xor(af[k], 16);
        af[k] += __shfl_xor(af[k], 32);
    }

    if (slot == 0) {
        bf16x8 ps = *(const bf16x8*)(hin + (unsigned)r * (unsigned)OUT_F + 8 * fe);
        float rr[8];
        #pragma unroll
        for (int k = 0; k < 8; ++k)
            rr[k] = 0.99f * af[k] + 0.01f * bf2f((unsigned short)ps[k]);
        size_t o = (size_t)r * OUT_F + 8 * fe;
        if (is_final) {
            *(float4*)(fout + o)     = make_float4(rr[0], rr[1], rr[2], rr[3]);
            *(float4*)(fout + o + 4) = make_float4(rr[4], rr[5], rr[6], rr[7]);
        } else {
            union { bf16x8 v; unsigned short u[8]; } pk;
            #pragma unroll
            for (int k = 0; k < 8; ++k) pk.u[k] = f2bf(rr[k]);
            *(bf16x8*)(hout + o) = pk.v;
        }
    }
}

extern "C" void kernel_launch(void* const* d_in, const int* in_sizes, int n_in,
                              void* d_out, int out_size, void* d_ws, size_t ws_size,
                              hipStream_t stream) {
    (void)in_sizes; (void)n_in; (void)out_size; (void)ws_size;
    const float* x  = (const float*)d_in[0];
    const float* W1 = (const float*)d_in[1];
    const float* b1 = (const float*)d_in[2];
    const float* W2 = (const float*)d_in[3];
    const float* b2 = (const float*)d_in[4];
    const float* ew = (const float*)d_in[5];
    const int*  row = (const int*)d_in[6];
    const int*  col = (const int*)d_in[7];
    float* out = (float*)d_out;

    char* ws = (char*)d_ws;
    size_t off = 0;
    auto alloc = [&](size_t b) { char* p = ws + off; off += (b + 255) & ~(size_t)255; return p; };
    // Region A: xb (102.4MB, lifetime cast_x..gemm1) aliases
    // tmp (25.6MB) + colw (25.6MB) (lifetime bucket_scatter..end).
    char* regionA = alloc((size_t)N_NODES * IN_F * 2);
    unsigned short* xb  = (unsigned short*)regionA;
    uint2* tmp  = (uint2*)regionA;
    int2*  colw = (int2*)(regionA + (size_t)N_EDGES * 8);
    unsigned short* w1t = (unsigned short*)alloc((size_t)IN_F * HID_F * 2);
    unsigned short* w2t = (unsigned short*)alloc((size_t)HID_F * OUT_F * 2);
    unsigned short* h1  = (unsigned short*)alloc((size_t)N_NODES * HID_F * 2);
    unsigned short* hb0 = (unsigned short*)alloc((size_t)N_NODES * OUT_F * 2);
    unsigned short* hb1 = (unsigned short*)alloc((size_t)N_NODES * OUT_F * 2);
    int*  rowptr = (int*)alloc((size_t)(N_NODES + 1) * 4);
    int*  cnt8   = (int*)alloc((size_t)8 * N_NODES * 4);
    int*  bsum   = (int*)alloc(512 * 4);
    int*  boff   = (int*)alloc(512 * 4);
    int*  pcnt   = (int*)alloc((size_t)8 * NBKT * 4);
    int*  pcur   = (int*)alloc((size_t)8 * NBKT * 4);

    const int NB = (N_NODES + 255) / 256;   // 391
    const int EB = (N_EDGES + 255) / 256;   // 12500 — shared by count & scatter

    cast_transpose_w1<<<(IN_F * HID_F + 255) / 256, 256, 0, stream>>>(W1, w1t);
    cast_transpose_w2<<<(HID_F * OUT_F + 255) / 256, 256, 0, stream>>>(W2, w2t);
    cast_x<<<(N_NODES * IN_F / 8 + 255) / 256, 256, 0, stream>>>(x, xb);
    gemm1<<<(N_NODES + 63) / 64, 512, 0, stream>>>(xb, w1t, b1, h1);
    gemm2<<<(N_NODES + 63) / 64, 256, 0, stream>>>(h1, w2t, b2, hb0);

    hipMemsetAsync(cnt8, 0, (size_t)8 * N_NODES * 4, stream);
    hipMemsetAsync(pcnt, 0, (size_t)8 * NBKT * 4, stream);
    count_edges<<<EB, 256, 0, stream>>>(row, cnt8, pcnt);
    scan_local<<<NB, 256, 0, stream>>>(cnt8, rowptr, bsum, N_NODES);
    scan_bsum<<<1, 512, 0, stream>>>(bsum, boff, NB);
    scan_add<<<NB, 256, 0, stream>>>(rowptr, boff, N_NODES);
    pcur_init<<<(NBKT + 255) / 256, 256, 0, stream>>>(rowptr, pcnt, pcur);
    bucket_scatter<<<EB, 256, 0, stream>>>(row, col, ew, pcur, tmp);
    bucket_sort<<<NBKT, 256, 0, stream>>>(tmp, rowptr, colw);

    const unsigned short* pin = hb0;
    for (int s = 0; s < 10; ++s) {
        int last = (s == 9);
        unsigned short* pout = (s & 1) ? hb0 : hb1;
        prop<<<N_NODES / 4, 256, 0, stream>>>(pin, rowptr, colw, pout, out, last);
        pin = pout;
    }
}

// Round 6
// 1201.432 us; speedup vs baseline: 1.3798x; 1.2423x over previous
//
#include <hip/hip_runtime.h>

// APPNP: h0 = relu(x@W1+b1)@W2+b2 ; 10x h = 0.99*SpMM(h) + 0.01*h
// bf16 MFMA GEMMs, on-device CSR build, gather SpMM with bf16 h storage.
// R6/R7 post-mortems: cross-XCD shared-line writes amplify ~8x; nt hints bad.
// R9 post-mortem: XCD-partitioning counters did NOTHING (WRITE_SIZE
//     byte-identical 187MB): device-scope atomicAdd is write-through past
//     L2 (coherence point = memory side), ~30B fabric write per atomic,
//     ~26G atomics/s cap. Counter locality is irrelevant; only the atomic
//     COUNT matters (R7 1/edge ~120us -> R8 2/edge ~240us).
// R10: eliminate global atomics from CSR build:
//     - fixed-capacity bucket segments (CAP=4096 vs mean 2048, >40 sigma)
//       -> no count_edges, no 100K-row scan, no memsets;
//     - bucket_scatter block-aggregates: LDS histogram per 12800-edge
//       block, ONE atomicAdd per (block,bucket) range-reserve (~390K
//       atomics, 16x fewer), place via LDS cursors;
//     - bucket_sort computes per-row rowptr locally (LDS 64-bin
//       histogram + wave scan), zero global atomics;
//     - 1-wave scan over 1563 bucket totals replaces 3-kernel scan.

#define N_NODES 100000
#define N_EDGES 3200000
#define IN_F    512
#define HID_F   256
#define OUT_F   64
#define NBKT    ((N_NODES + 63) / 64)   // 1563 coarse buckets (row>>6)
#define CAP     4096                     // slots per bucket segment
#define SBLK    250                      // scatter blocks
#define SCHUNK  12800                    // edges per scatter block (250*12800=3.2M)

typedef short bf16x8 __attribute__((ext_vector_type(8)));
typedef float f32x4  __attribute__((ext_vector_type(4)));

__device__ __forceinline__ unsigned short f2bf(float f) {
    unsigned int u = __float_as_uint(f);
    unsigned int r = (u + 0x7FFFu + ((u >> 16) & 1u)) >> 16;  // RNE
    return (unsigned short)r;
}
__device__ __forceinline__ float bf2f(unsigned short h) {
    return __uint_as_float(((unsigned int)h) << 16);
}

// ---------------- weight cast+transpose ----------------
__global__ void cast_transpose_w1(const float* __restrict__ w, unsigned short* __restrict__ wt) {
    int idx = blockIdx.x * blockDim.x + threadIdx.x;   // over 512*256
    if (idx >= IN_F * HID_F) return;
    int k = idx / HID_F, n = idx % HID_F;
    wt[(size_t)n * IN_F + k] = f2bf(w[idx]);           // W1T [HID_F][IN_F]
}
__global__ void cast_transpose_w2(const float* __restrict__ w, unsigned short* __restrict__ wt) {
    int idx = blockIdx.x * blockDim.x + threadIdx.x;   // over 256*64
    if (idx >= HID_F * OUT_F) return;
    int k = idx / OUT_F, n = idx % OUT_F;
    wt[(size_t)n * HID_F + k] = f2bf(w[idx]);          // W2T [OUT_F][HID_F]
}

// ---------------- x cast: fp32 -> bf16, coalesced stream ----------------
__global__ __launch_bounds__(256) void cast_x(const float* __restrict__ x,
                                              unsigned short* __restrict__ xb) {
    int idx = blockIdx.x * 256 + threadIdx.x;          // octet index, 6.4M total
    if (idx >= N_NODES * IN_F / 8) return;
    const float4* s = (const float4*)(x + (size_t)idx * 8);
    float4 f0 = s[0], f1 = s[1];
    union { bf16x8 v; unsigned short u[8]; } t;
    t.u[0] = f2bf(f0.x); t.u[1] = f2bf(f0.y); t.u[2] = f2bf(f0.z); t.u[3] = f2bf(f0.w);
    t.u[4] = f2bf(f1.x); t.u[5] = f2bf(f1.y); t.u[6] = f2bf(f1.z); t.u[7] = f2bf(f1.w);
    *(bf16x8*)(xb + (size_t)idx * 8) = t.v;
}

// ---------------- GEMM1: h1 = relu(xb @ W1 + b1), bf16 in/out ----------------
__global__ __launch_bounds__(512) void gemm1(const unsigned short* __restrict__ xb,
                                             const unsigned short* __restrict__ w1t,
                                             const float* __restrict__ b1,
                                             unsigned short* __restrict__ h1) {
    int tid  = threadIdx.x;
    int lane = tid & 63;
    int w    = tid >> 6;     // 0..7
    int wm   = w >> 2;       // 0..1
    int wn   = w & 3;        // 0..3
    int quad = lane >> 4;    // 0..3
    int lm   = lane & 15;
    int m0 = blockIdx.x * 64 + wm * 32;
    int n0 = wn * 64;

    f32x4 acc[2][4];
    for (int i = 0; i < 2; ++i)
        for (int j = 0; j < 4; ++j)
            acc[i][j] = (f32x4){0.f, 0.f, 0.f, 0.f};

    for (int kk = 0; kk < IN_F; kk += 32) {
        bf16x8 a[2], b[4];
        for (int i = 0; i < 2; ++i) {
            int m = m0 + i * 16 + lm;
            if (m > N_NODES - 1) m = N_NODES - 1;            // clamp loads, mask stores
            a[i] = *(const bf16x8*)(xb + (size_t)m * IN_F + kk + quad * 8);
        }
        for (int j = 0; j < 4; ++j) {
            int n = n0 + j * 16 + lm;
            b[j] = *(const bf16x8*)(w1t + (size_t)n * IN_F + kk + quad * 8);
        }
        for (int i = 0; i < 2; ++i)
            for (int j = 0; j < 4; ++j)
                acc[i][j] = __builtin_amdgcn_mfma_f32_16x16x32_bf16(a[i], b[j], acc[i][j], 0, 0, 0);
    }

    for (int i = 0; i < 2; ++i)
        for (int j = 0; j < 4; ++j) {
            int n = n0 + j * 16 + lm;
            float bias = b1[n];
            for (int r = 0; r < 4; ++r) {
                int m = m0 + i * 16 + quad * 4 + r;   // C/D: row=(lane>>4)*4+reg, col=lane&15
                if (m < N_NODES) {
                    float v = acc[i][j][r] + bias;
                    v = v > 0.f ? v : 0.f;
                    h1[(size_t)m * HID_F + n] = f2bf(v);
                }
            }
        }
}

// ---------------- GEMM2: h0 = h1 @ W2 + b2, bf16 out ----------------
__global__ __launch_bounds__(256) void gemm2(const unsigned short* __restrict__ h1,
                                             const unsigned short* __restrict__ w2t,
                                             const float* __restrict__ b2,
                                             unsigned short* __restrict__ h0) {
    int tid  = threadIdx.x;
    int lane = tid & 63;
    int w    = tid >> 6;     // 0..3
    int wm   = w >> 1;       // 0..1
    int wn   = w & 1;        // 0..1
    int quad = lane >> 4;
    int lm   = lane & 15;
    int m0 = blockIdx.x * 64 + wm * 32;
    int n0 = wn * 32;

    f32x4 acc[2][2];
    for (int i = 0; i < 2; ++i)
        for (int j = 0; j < 2; ++j)
            acc[i][j] = (f32x4){0.f, 0.f, 0.f, 0.f};

    for (int kk = 0; kk < HID_F; kk += 32) {
        bf16x8 a[2], b[2];
        for (int i = 0; i < 2; ++i) {
            int m = m0 + i * 16 + lm;
            if (m > N_NODES - 1) m = N_NODES - 1;
            a[i] = *(const bf16x8*)(h1 + (size_t)m * HID_F + kk + quad * 8);
        }
        for (int j = 0; j < 2; ++j) {
            int n = n0 + j * 16 + lm;
            b[j] = *(const bf16x8*)(w2t + (size_t)n * HID_F + kk + quad * 8);
        }
        for (int i = 0; i < 2; ++i)
            for (int j = 0; j < 2; ++j)
                acc[i][j] = __builtin_amdgcn_mfma_f32_16x16x32_bf16(a[i], b[j], acc[i][j], 0, 0, 0);
    }

    for (int i = 0; i < 2; ++i)
        for (int j = 0; j < 2; ++j) {
            int n = n0 + j * 16 + lm;
            float bias = b2[n];
            for (int r = 0; r < 4; ++r) {
                int m = m0 + i * 16 + quad * 4 + r;
                if (m < N_NODES) {
                    float v = acc[i][j][r] + bias;
                    h0[(size_t)m * OUT_F + n] = f2bf(v);
                }
            }
        }
}

// ---------------- CSR build (atomic-minimized) ----------------
__global__ void bs_init(int* __restrict__ cur) {
    int c = blockIdx.x * blockDim.x + threadIdx.x;
    if (c < NBKT) cur[c] = c * CAP;
}

// Block-aggregated scatter: each block owns SCHUNK consecutive edges.
// Pass 1: LDS histogram over the 1563 buckets. Reserve: ONE global
// atomicAdd per (block,bucket) (~390K total, vs 3.2M per-edge). Pass 2:
// re-read edges, place at lbase[c] + LDS cursor. Per-edge positioning is
// entirely in LDS; global atomic count is 16x smaller (the R9 lesson:
// device atomics are write-through fabric ops, count is all that matters).
__global__ __launch_bounds__(256) void bucket_scatter(const int* __restrict__ row,
                                                      const int* __restrict__ col,
                                                      const float* __restrict__ ew,
                                                      int* __restrict__ cur,
                                                      uint2* __restrict__ tmp) {
    __shared__ int lh[NBKT];   // histogram, then reserved base
    __shared__ int lc[NBKT];   // local cursor
    int tid = threadIdx.x;
    int e0 = blockIdx.x * SCHUNK;

    for (int c = tid; c < NBKT; c += 256) { lh[c] = 0; lc[c] = 0; }
    __syncthreads();
    for (int i = tid; i < SCHUNK; i += 256)
        atomicAdd(&lh[row[e0 + i] >> 6], 1);
    __syncthreads();
    for (int c = tid; c < NBKT; c += 256) {
        int n = lh[c];
        if (n) lh[c] = atomicAdd(&cur[c], n);   // lh[c] becomes global base
    }
    __syncthreads();
    for (int i = tid; i < SCHUNK; i += 256) {
        int e = e0 + i;
        int r = row[e];
        int c = r >> 6;
        int p = lh[c] + atomicAdd(&lc[c], 1);
        if (p < (c + 1) * CAP)   // safety clamp (CAP=4096 vs mean 2048, >40 sigma)
            tmp[p] = make_uint2((unsigned)col[e] | ((unsigned)(r & 63) << 17),
                                __float_as_uint(ew[e]));
    }
}

// Single-wave scan over 1563 bucket totals -> bktbase (exclusive), plus
// rowptr[N_NODES] = E (rows past N-1 in the last bucket have zero count).
__global__ __launch_bounds__(64) void bkt_scan(const int* __restrict__ cur,
                                               int* __restrict__ bktbase,
                                               int* __restrict__ rowptr) {
    int lane = threadIdx.x;
    int carry = 0;
    for (int base = 0; base < NBKT; base += 64) {
        int c = base + lane;
        int v = (c < NBKT) ? (cur[c] - c * CAP) : 0;
        int incl = v;
        for (int d = 1; d < 64; d <<= 1) {
            int t = __shfl_up(incl, d);
            if (lane >= d) incl += t;
        }
        if (c < NBKT) bktbase[c] = carry + incl - v;
        carry += __shfl(incl, 63);
    }
    if (lane == 0) { bktbase[NBKT] = carry; rowptr[N_NODES] = carry; }
}

// Pass B: one block per bucket. Two passes over the bucket's segment:
// (1) LDS 64-bin row histogram; wave-scan -> per-row rowptr (no global
// scan kernel needed); (2) place edges via LDS cursors. Zero global
// atomics.
__global__ __launch_bounds__(256) void bucket_sort(const uint2* __restrict__ tmp,
                                                   const int* __restrict__ bktbase,
                                                   int* __restrict__ rowptr,
                                                   int2* __restrict__ colw) {
    __shared__ int rh[64];
    __shared__ int lcur[64];
    int c = blockIdx.x;
    int tid = threadIdx.x;
    int s = c * CAP;
    int base = bktbase[c];
    int tot = bktbase[c + 1] - base;

    if (tid < 64) rh[tid] = 0;
    __syncthreads();
    for (int i = tid; i < tot; i += 256)
        atomicAdd(&rh[(tmp[s + i].x >> 17) & 63], 1);
    __syncthreads();
    if (tid < 64) {
        int v = rh[tid];
        int incl = v;
        for (int d = 1; d < 64; d <<= 1) {
            int t = __shfl_up(incl, d);
            if (tid >= d) incl += t;
        }
        int excl = incl - v;
        int rr = c * 64 + tid;
        if (rr < N_NODES) rowptr[rr] = base + excl;
        lcur[tid] = base + excl;
    }
    __syncthreads();
    for (int i = tid; i < tot; i += 256) {
        uint2 t = tmp[s + i];
        int rl = (t.x >> 17) & 63;
        int p = atomicAdd(&lcur[rl], 1);
        colw[p] = make_int2((int)(t.x & 0x1FFFF), (int)t.y);
    }
}

// ---------------- propagation ----------------
// One wave per row. 64 lanes = 8 edge-slots x 8 feature-octets.
// Lane (slot=lane>>3, fe=lane&7) handles features [8*fe, 8*fe+7] of edge
// slot: 16B bf16x8 gather per lane, 8 lanes cover a full 128B h-row.
__global__ __launch_bounds__(256) void prop(const unsigned short* __restrict__ hin,
                                            const int* __restrict__ rowptr,
                                            const int2* __restrict__ colw,
                                            unsigned short* __restrict__ hout,
                                            float* __restrict__ fout, int is_final) {
    int lane = threadIdx.x & 63;
    int r = blockIdx.x * 4 + (threadIdx.x >> 6);
    int fe   = lane & 7;     // feature octet index
    int slot = lane >> 3;    // 0..7

    int s = rowptr[r];
    int e = rowptr[r + 1];
    const unsigned short* hfe = hin + 8 * fe;

    float af[8];
    #pragma unroll
    for (int k = 0; k < 8; ++k) af[k] = 0.f;

    int n8 = (e - s) & ~7;
    int i = s;
    #pragma unroll 2
    for (; i < s + n8; i += 8) {
        int2 cw = colw[i + slot];
        float w = __int_as_float(cw.y);
        bf16x8 p = *(const bf16x8*)(hfe + (unsigned)cw.x * (unsigned)OUT_F);
        #pragma unroll
        for (int k = 0; k < 8; ++k)
            af[k] += w * bf2f((unsigned short)p[k]);
    }
    {   // tail (0..7 edges)
        int ei = i + slot;
        if (ei < e) {
            int2 cw = colw[ei];
            float w = __int_as_float(cw.y);
            bf16x8 p = *(const bf16x8*)(hfe + (unsigned)cw.x * (unsigned)OUT_F);
            #pragma unroll
            for (int k = 0; k < 8; ++k)
                af[k] += w * bf2f((unsigned short)p[k]);
        }
    }
    // combine the 8 edge-slots
    #pragma unroll
    for (int k = 0; k < 8; ++k) {
        af[k] += __shfl_xor(af[k], 8);
        af[k] += __shfl_xor(af[k], 16);
        af[k] += __shfl_xor(af[k], 32);
    }

    if (slot == 0) {
        bf16x8 ps = *(const bf16x8*)(hin + (unsigned)r * (unsigned)OUT_F + 8 * fe);
        float rr[8];
        #pragma unroll
        for (int k = 0; k < 8; ++k)
            rr[k] = 0.99f * af[k] + 0.01f * bf2f((unsigned short)ps[k]);
        size_t o = (size_t)r * OUT_F + 8 * fe;
        if (is_final) {
            *(float4*)(fout + o)     = make_float4(rr[0], rr[1], rr[2], rr[3]);
            *(float4*)(fout + o + 4) = make_float4(rr[4], rr[5], rr[6], rr[7]);
        } else {
            union { bf16x8 v; unsigned short u[8]; } pk;
            #pragma unroll
            for (int k = 0; k < 8; ++k) pk.u[k] = f2bf(rr[k]);
            *(bf16x8*)(hout + o) = pk.v;
        }
    }
}

extern "C" void kernel_launch(void* const* d_in, const int* in_sizes, int n_in,
                              void* d_out, int out_size, void* d_ws, size_t ws_size,
                              hipStream_t stream) {
    (void)in_sizes; (void)n_in; (void)out_size; (void)ws_size;
    const float* x  = (const float*)d_in[0];
    const float* W1 = (const float*)d_in[1];
    const float* b1 = (const float*)d_in[2];
    const float* W2 = (const float*)d_in[3];
    const float* b2 = (const float*)d_in[4];
    const float* ew = (const float*)d_in[5];
    const int*  row = (const int*)d_in[6];
    const int*  col = (const int*)d_in[7];
    float* out = (float*)d_out;

    char* ws = (char*)d_ws;
    size_t off = 0;
    auto alloc = [&](size_t b) { char* p = ws + off; off += (b + 255) & ~(size_t)255; return p; };
    // Region A: xb (102.4MB, lifetime cast_x..gemm1) aliases
    // tmp (CAP segments, 51.2MB) + colw (25.6MB), lifetime scatter..end.
    char* regionA = alloc((size_t)N_NODES * IN_F * 2);
    unsigned short* xb  = (unsigned short*)regionA;
    uint2* tmp  = (uint2*)regionA;
    int2*  colw = (int2*)(regionA + (size_t)NBKT * CAP * 8);
    unsigned short* w1t = (unsigned short*)alloc((size_t)IN_F * HID_F * 2);
    unsigned short* w2t = (unsigned short*)alloc((size_t)HID_F * OUT_F * 2);
    unsigned short* h1  = (unsigned short*)alloc((size_t)N_NODES * HID_F * 2);
    unsigned short* hb0 = (unsigned short*)alloc((size_t)N_NODES * OUT_F * 2);
    unsigned short* hb1 = (unsigned short*)alloc((size_t)N_NODES * OUT_F * 2);
    int*  rowptr  = (int*)alloc((size_t)(N_NODES + 1) * 4);
    int*  cur     = (int*)alloc((size_t)NBKT * 4);
    int*  bktbase = (int*)alloc((size_t)(NBKT + 1) * 4);

    cast_transpose_w1<<<(IN_F * HID_F + 255) / 256, 256, 0, stream>>>(W1, w1t);
    cast_transpose_w2<<<(HID_F * OUT_F + 255) / 256, 256, 0, stream>>>(W2, w2t);
    cast_x<<<(N_NODES * IN_F / 8 + 255) / 256, 256, 0, stream>>>(x, xb);
    gemm1<<<(N_NODES + 63) / 64, 512, 0, stream>>>(xb, w1t, b1, h1);
    gemm2<<<(N_NODES + 63) / 64, 256, 0, stream>>>(h1, w2t, b2, hb0);

    bs_init<<<(NBKT + 255) / 256, 256, 0, stream>>>(cur);
    bucket_scatter<<<SBLK, 256, 0, stream>>>(row, col, ew, cur, tmp);
    bkt_scan<<<1, 64, 0, stream>>>(cur, bktbase, rowptr);
    bucket_sort<<<NBKT, 256, 0, stream>>>(tmp, bktbase, rowptr, colw);

    const unsigned short* pin = hb0;
    for (int s = 0; s < 10; ++s) {
        int last = (s == 9);
        unsigned short* pout = (s & 1) ? hb0 : hb1;
        prop<<<N_NODES / 4, 256, 0, stream>>>(pin, rowptr, colw, pout, out, last);
        pin = pout;
    }
}

// Round 7
// 1107.317 us; speedup vs baseline: 1.4971x; 1.0850x over previous
//
#include <hip/hip_runtime.h>

// APPNP: h0 = relu(x@W1+b1)@W2+b2 ; 10x h = 0.99*SpMM(h) + 0.01*h
// bf16 MFMA GEMMs, on-device CSR build, gather SpMM with bf16 h storage.
// R6/R7: cross-XCD shared-line writes amplify ~8x; nt hints all bad.
// R9: device-scope atomicAdd is write-through past L2 (~30B fabric write
//     per atomic, ~26G/s cap); only atomic COUNT matters.
// R10: atomic-minimized CSR build (block-aggregated reservation, fixed
//     CAP=4096 bucket segments, LDS histograms) — 1492 -> 1201 us.
// R11: gemm1 was latency-bound (165us, MfmaUtil 6%, VALU 5%, HBM 8%,
//     VGPR=44 -> zero pipelining; no LDS staging, 6 dependent global
//     loads per K-step per wave; W1T re-fetched 400MB). Rewritten as
//     canonical tiled GEMM: 128x128 tile, BK=32, 4 waves (64x64 each,
//     4x4 frags), double-buffered LDS, reg-staged global->LDS issued
//     one step ahead, +8 elem LDS pad (<=2-way bank aliasing).

#define N_NODES 100000
#define N_EDGES 3200000
#define IN_F    512
#define HID_F   256
#define OUT_F   64
#define NBKT    ((N_NODES + 63) / 64)   // 1563 coarse buckets (row>>6)
#define CAP     4096                     // slots per bucket segment
#define SBLK    250                      // scatter blocks
#define SCHUNK  12800                    // edges per scatter block

#define BM 128
#define BN 128
#define BK 32
#define LDK 40                           // padded LDS row (bf16 elems)

typedef short bf16x8 __attribute__((ext_vector_type(8)));
typedef float f32x4  __attribute__((ext_vector_type(4)));

__device__ __forceinline__ unsigned short f2bf(float f) {
    unsigned int u = __float_as_uint(f);
    unsigned int r = (u + 0x7FFFu + ((u >> 16) & 1u)) >> 16;  // RNE
    return (unsigned short)r;
}
__device__ __forceinline__ float bf2f(unsigned short h) {
    return __uint_as_float(((unsigned int)h) << 16);
}

// ---------------- weight cast+transpose ----------------
__global__ void cast_transpose_w1(const float* __restrict__ w, unsigned short* __restrict__ wt) {
    int idx = blockIdx.x * blockDim.x + threadIdx.x;   // over 512*256
    if (idx >= IN_F * HID_F) return;
    int k = idx / HID_F, n = idx % HID_F;
    wt[(size_t)n * IN_F + k] = f2bf(w[idx]);           // W1T [HID_F][IN_F]
}
__global__ void cast_transpose_w2(const float* __restrict__ w, unsigned short* __restrict__ wt) {
    int idx = blockIdx.x * blockDim.x + threadIdx.x;   // over 256*64
    if (idx >= HID_F * OUT_F) return;
    int k = idx / OUT_F, n = idx % OUT_F;
    wt[(size_t)n * HID_F + k] = f2bf(w[idx]);          // W2T [OUT_F][HID_F]
}

// ---------------- x cast: fp32 -> bf16, coalesced stream ----------------
__global__ __launch_bounds__(256) void cast_x(const float* __restrict__ x,
                                              unsigned short* __restrict__ xb) {
    int idx = blockIdx.x * 256 + threadIdx.x;          // octet index, 6.4M total
    if (idx >= N_NODES * IN_F / 8) return;
    const float4* s = (const float4*)(x + (size_t)idx * 8);
    float4 f0 = s[0], f1 = s[1];
    union { bf16x8 v; unsigned short u[8]; } t;
    t.u[0] = f2bf(f0.x); t.u[1] = f2bf(f0.y); t.u[2] = f2bf(f0.z); t.u[3] = f2bf(f0.w);
    t.u[4] = f2bf(f1.x); t.u[5] = f2bf(f1.y); t.u[6] = f2bf(f1.z); t.u[7] = f2bf(f1.w);
    *(bf16x8*)(xb + (size_t)idx * 8) = t.v;
}

// ---------------- GEMM1: h1 = relu(xb @ W1 + b1), tiled+LDS ----------------
// grid: (ceil(M/128)) * 2 blocks; blockIdx>>1 = m-tile, blockIdx&1 = n-half.
__global__ __launch_bounds__(256) void gemm1(const unsigned short* __restrict__ xb,
                                             const unsigned short* __restrict__ w1t,
                                             const float* __restrict__ b1,
                                             unsigned short* __restrict__ h1) {
    __shared__ unsigned short lA[2][BM][LDK];
    __shared__ unsigned short lB[2][BN][LDK];

    int tid  = threadIdx.x;
    int bm0  = (blockIdx.x >> 1) * BM;
    int n0   = (blockIdx.x & 1) * BN;
    int lane = tid & 63;
    int w    = tid >> 6;      // 0..3
    int wm   = w >> 1;        // 0..1
    int wn   = w & 1;         // 0..1
    int quad = lane >> 4;     // 0..3
    int lm   = lane & 15;

    // staging coords: thread t -> row sr=t>>2 (+64 for j=1), octet sq=(t&3)*8
    int sr = tid >> 2;        // 0..63
    int sq = (tid & 3) * 8;

    f32x4 acc[4][4];
    #pragma unroll
    for (int i = 0; i < 4; ++i)
        #pragma unroll
        for (int j = 0; j < 4; ++j)
            acc[i][j] = (f32x4){0.f, 0.f, 0.f, 0.f};

    bf16x8 ra[2], rb[2];
    // prologue: load K-step 0, write buf 0
    #pragma unroll
    for (int j = 0; j < 2; ++j) {
        int m = bm0 + sr + j * 64; if (m > N_NODES - 1) m = N_NODES - 1;
        ra[j] = *(const bf16x8*)(xb  + (size_t)m * IN_F + sq);
        rb[j] = *(const bf16x8*)(w1t + (size_t)(n0 + sr + j * 64) * IN_F + sq);
    }
    #pragma unroll
    for (int j = 0; j < 2; ++j) {
        *(bf16x8*)&lA[0][sr + j * 64][sq] = ra[j];
        *(bf16x8*)&lB[0][sr + j * 64][sq] = rb[j];
    }
    __syncthreads();

    int cur = 0;
    for (int step = 0; step < IN_F / BK; ++step) {
        // issue next step's global loads before this step's MFMAs (overlap)
        if (step + 1 < IN_F / BK) {
            int kn = (step + 1) * BK;
            #pragma unroll
            for (int j = 0; j < 2; ++j) {
                int m = bm0 + sr + j * 64; if (m > N_NODES - 1) m = N_NODES - 1;
                ra[j] = *(const bf16x8*)(xb  + (size_t)m * IN_F + kn + sq);
                rb[j] = *(const bf16x8*)(w1t + (size_t)(n0 + sr + j * 64) * IN_F + kn + sq);
            }
        }
        // compute from buf[cur]
        bf16x8 af[4], bfr[4];
        #pragma unroll
        for (int i = 0; i < 4; ++i)
            af[i] = *(const bf16x8*)&lA[cur][wm * 64 + i * 16 + lm][quad * 8];
        #pragma unroll
        for (int j = 0; j < 4; ++j)
            bfr[j] = *(const bf16x8*)&lB[cur][wn * 64 + j * 16 + lm][quad * 8];
        #pragma unroll
        for (int i = 0; i < 4; ++i)
            #pragma unroll
            for (int j = 0; j < 4; ++j)
                acc[i][j] = __builtin_amdgcn_mfma_f32_16x16x32_bf16(af[i], bfr[j], acc[i][j], 0, 0, 0);
        // write next buffer, one barrier per step (see R11 note)
        if (step + 1 < IN_F / BK) {
            #pragma unroll
            for (int j = 0; j < 2; ++j) {
                *(bf16x8*)&lA[cur ^ 1][sr + j * 64][sq] = ra[j];
                *(bf16x8*)&lB[cur ^ 1][sr + j * 64][sq] = rb[j];
            }
            __syncthreads();
            cur ^= 1;
        }
    }

    #pragma unroll
    for (int i = 0; i < 4; ++i)
        #pragma unroll
        for (int j = 0; j < 4; ++j) {
            int n = n0 + wn * 64 + j * 16 + lm;
            float bias = b1[n];
            #pragma unroll
            for (int r = 0; r < 4; ++r) {
                int m = bm0 + wm * 64 + i * 16 + quad * 4 + r;  // C/D: row=(lane>>4)*4+reg
                if (m < N_NODES) {
                    float v = acc[i][j][r] + bias;
                    v = v > 0.f ? v : 0.f;
                    h1[(size_t)m * HID_F + n] = f2bf(v);
                }
            }
        }
}

// ---------------- GEMM2: h0 = h1 @ W2 + b2, bf16 out ----------------
__global__ __launch_bounds__(256) void gemm2(const unsigned short* __restrict__ h1,
                                             const unsigned short* __restrict__ w2t,
                                             const float* __restrict__ b2,
                                             unsigned short* __restrict__ h0) {
    int tid  = threadIdx.x;
    int lane = tid & 63;
    int w    = tid >> 6;     // 0..3
    int wm   = w >> 1;       // 0..1
    int wn   = w & 1;        // 0..1
    int quad = lane >> 4;
    int lm   = lane & 15;
    int m0 = blockIdx.x * 64 + wm * 32;
    int n0 = wn * 32;

    f32x4 acc[2][2];
    for (int i = 0; i < 2; ++i)
        for (int j = 0; j < 2; ++j)
            acc[i][j] = (f32x4){0.f, 0.f, 0.f, 0.f};

    for (int kk = 0; kk < HID_F; kk += 32) {
        bf16x8 a[2], b[2];
        for (int i = 0; i < 2; ++i) {
            int m = m0 + i * 16 + lm;
            if (m > N_NODES - 1) m = N_NODES - 1;
            a[i] = *(const bf16x8*)(h1 + (size_t)m * HID_F + kk + quad * 8);
        }
        for (int j = 0; j < 2; ++j) {
            int n = n0 + j * 16 + lm;
            b[j] = *(const bf16x8*)(w2t + (size_t)n * HID_F + kk + quad * 8);
        }
        for (int i = 0; i < 2; ++i)
            for (int j = 0; j < 2; ++j)
                acc[i][j] = __builtin_amdgcn_mfma_f32_16x16x32_bf16(a[i], b[j], acc[i][j], 0, 0, 0);
    }

    for (int i = 0; i < 2; ++i)
        for (int j = 0; j < 2; ++j) {
            int n = n0 + j * 16 + lm;
            float bias = b2[n];
            for (int r = 0; r < 4; ++r) {
                int m = m0 + i * 16 + quad * 4 + r;
                if (m < N_NODES) {
                    float v = acc[i][j][r] + bias;
                    h0[(size_t)m * OUT_F + n] = f2bf(v);
                }
            }
        }
}

// ---------------- CSR build (atomic-minimized) ----------------
__global__ void bs_init(int* __restrict__ cur) {
    int c = blockIdx.x * blockDim.x + threadIdx.x;
    if (c < NBKT) cur[c] = c * CAP;
}

// Block-aggregated scatter: LDS histogram per 12800-edge block, ONE
// global atomicAdd per (block,bucket) range-reserve, place via LDS.
__global__ __launch_bounds__(256) void bucket_scatter(const int* __restrict__ row,
                                                      const int* __restrict__ col,
                                                      const float* __restrict__ ew,
                                                      int* __restrict__ cur,
                                                      uint2* __restrict__ tmp) {
    __shared__ int lh[NBKT];   // histogram, then reserved base
    __shared__ int lc[NBKT];   // local cursor
    int tid = threadIdx.x;
    int e0 = blockIdx.x * SCHUNK;

    for (int c = tid; c < NBKT; c += 256) { lh[c] = 0; lc[c] = 0; }
    __syncthreads();
    for (int i = tid; i < SCHUNK; i += 256)
        atomicAdd(&lh[row[e0 + i] >> 6], 1);
    __syncthreads();
    for (int c = tid; c < NBKT; c += 256) {
        int n = lh[c];
        if (n) lh[c] = atomicAdd(&cur[c], n);   // lh[c] becomes global base
    }
    __syncthreads();
    for (int i = tid; i < SCHUNK; i += 256) {
        int e = e0 + i;
        int r = row[e];
        int c = r >> 6;
        int p = lh[c] + atomicAdd(&lc[c], 1);
        if (p < (c + 1) * CAP)   // safety clamp (CAP=4096 vs mean 2048)
            tmp[p] = make_uint2((unsigned)col[e] | ((unsigned)(r & 63) << 17),
                                __float_as_uint(ew[e]));
    }
}

// Single-wave scan over 1563 bucket totals -> bktbase (exclusive) + rowptr[N]=E.
__global__ __launch_bounds__(64) void bkt_scan(const int* __restrict__ cur,
                                               int* __restrict__ bktbase,
                                               int* __restrict__ rowptr) {
    int lane = threadIdx.x;
    int carry = 0;
    for (int base = 0; base < NBKT; base += 64) {
        int c = base + lane;
        int v = (c < NBKT) ? (cur[c] - c * CAP) : 0;
        int incl = v;
        for (int d = 1; d < 64; d <<= 1) {
            int t = __shfl_up(incl, d);
            if (lane >= d) incl += t;
        }
        if (c < NBKT) bktbase[c] = carry + incl - v;
        carry += __shfl(incl, 63);
    }
    if (lane == 0) { bktbase[NBKT] = carry; rowptr[N_NODES] = carry; }
}

// Pass B: one block per bucket; LDS 64-bin row histogram + wave scan ->
// per-row rowptr; place edges via LDS cursors. Zero global atomics.
__global__ __launch_bounds__(256) void bucket_sort(const uint2* __restrict__ tmp,
                                                   const int* __restrict__ bktbase,
                                                   int* __restrict__ rowptr,
                                                   int2* __restrict__ colw) {
    __shared__ int rh[64];
    __shared__ int lcur[64];
    int c = blockIdx.x;
    int tid = threadIdx.x;
    int s = c * CAP;
    int base = bktbase[c];
    int tot = bktbase[c + 1] - base;

    if (tid < 64) rh[tid] = 0;
    __syncthreads();
    for (int i = tid; i < tot; i += 256)
        atomicAdd(&rh[(tmp[s + i].x >> 17) & 63], 1);
    __syncthreads();
    if (tid < 64) {
        int v = rh[tid];
        int incl = v;
        for (int d = 1; d < 64; d <<= 1) {
            int t = __shfl_up(incl, d);
            if (tid >= d) incl += t;
        }
        int excl = incl - v;
        int rr = c * 64 + tid;
        if (rr < N_NODES) rowptr[rr] = base + excl;
        lcur[tid] = base + excl;
    }
    __syncthreads();
    for (int i = tid; i < tot; i += 256) {
        uint2 t = tmp[s + i];
        int rl = (t.x >> 17) & 63;
        int p = atomicAdd(&lcur[rl], 1);
        colw[p] = make_int2((int)(t.x & 0x1FFFF), (int)t.y);
    }
}

// ---------------- propagation ----------------
// One wave per row. 64 lanes = 8 edge-slots x 8 feature-octets.
__global__ __launch_bounds__(256) void prop(const unsigned short* __restrict__ hin,
                                            const int* __restrict__ rowptr,
                                            const int2* __restrict__ colw,
                                            unsigned short* __restrict__ hout,
                                            float* __restrict__ fout, int is_final) {
    int lane = threadIdx.x & 63;
    int r = blockIdx.x * 4 + (threadIdx.x >> 6);
    int fe   = lane & 7;     // feature octet index
    int slot = lane >> 3;    // 0..7

    int s = rowptr[r];
    int e = rowptr[r + 1];
    const unsigned short* hfe = hin + 8 * fe;

    float af[8];
    #pragma unroll
    for (int k = 0; k < 8; ++k) af[k] = 0.f;

    int n8 = (e - s) & ~7;
    int i = s;
    #pragma unroll 2
    for (; i < s + n8; i += 8) {
        int2 cw = colw[i + slot];
        float w = __int_as_float(cw.y);
        bf16x8 p = *(const bf16x8*)(hfe + (unsigned)cw.x * (unsigned)OUT_F);
        #pragma unroll
        for (int k = 0; k < 8; ++k)
            af[k] += w * bf2f((unsigned short)p[k]);
    }
    {   // tail (0..7 edges)
        int ei = i + slot;
        if (ei < e) {
            int2 cw = colw[ei];
            float w = __int_as_float(cw.y);
            bf16x8 p = *(const bf16x8*)(hfe + (unsigned)cw.x * (unsigned)OUT_F);
            #pragma unroll
            for (int k = 0; k < 8; ++k)
                af[k] += w * bf2f((unsigned short)p[k]);
        }
    }
    // combine the 8 edge-slots
    #pragma unroll
    for (int k = 0; k < 8; ++k) {
        af[k] += __shfl_xor(af[k], 8);
        af[k] += __shfl_xor(af[k], 16);
        af[k] += __shfl_xor(af[k], 32);
    }

    if (slot == 0) {
        bf16x8 ps = *(const bf16x8*)(hin + (unsigned)r * (unsigned)OUT_F + 8 * fe);
        float rr[8];
        #pragma unroll
        for (int k = 0; k < 8; ++k)
            rr[k] = 0.99f * af[k] + 0.01f * bf2f((unsigned short)ps[k]);
        size_t o = (size_t)r * OUT_F + 8 * fe;
        if (is_final) {
            *(float4*)(fout + o)     = make_float4(rr[0], rr[1], rr[2], rr[3]);
            *(float4*)(fout + o + 4) = make_float4(rr[4], rr[5], rr[6], rr[7]);
        } else {
            union { bf16x8 v; unsigned short u[8]; } pk;
            #pragma unroll
            for (int k = 0; k < 8; ++k) pk.u[k] = f2bf(rr[k]);
            *(bf16x8*)(hout + o) = pk.v;
        }
    }
}

extern "C" void kernel_launch(void* const* d_in, const int* in_sizes, int n_in,
                              void* d_out, int out_size, void* d_ws, size_t ws_size,
                              hipStream_t stream) {
    (void)in_sizes; (void)n_in; (void)out_size; (void)ws_size;
    const float* x  = (const float*)d_in[0];
    const float* W1 = (const float*)d_in[1];
    const float* b1 = (const float*)d_in[2];
    const float* W2 = (const float*)d_in[3];
    const float* b2 = (const float*)d_in[4];
    const float* ew = (const float*)d_in[5];
    const int*  row = (const int*)d_in[6];
    const int*  col = (const int*)d_in[7];
    float* out = (float*)d_out;

    char* ws = (char*)d_ws;
    size_t off = 0;
    auto alloc = [&](size_t b) { char* p = ws + off; off += (b + 255) & ~(size_t)255; return p; };
    // Region A: xb (102.4MB, lifetime cast_x..gemm1) aliases
    // tmp (CAP segments, 51.2MB) + colw (25.6MB), lifetime scatter..end.
    char* regionA = alloc((size_t)N_NODES * IN_F * 2);
    unsigned short* xb  = (unsigned short*)regionA;
    uint2* tmp  = (uint2*)regionA;
    int2*  colw = (int2*)(regionA + (size_t)NBKT * CAP * 8);
    unsigned short* w1t = (unsigned short*)alloc((size_t)IN_F * HID_F * 2);
    unsigned short* w2t = (unsigned short*)alloc((size_t)HID_F * OUT_F * 2);
    unsigned short* h1  = (unsigned short*)alloc((size_t)N_NODES * HID_F * 2);
    unsigned short* hb0 = (unsigned short*)alloc((size_t)N_NODES * OUT_F * 2);
    unsigned short* hb1 = (unsigned short*)alloc((size_t)N_NODES * OUT_F * 2);
    int*  rowptr  = (int*)alloc((size_t)(N_NODES + 1) * 4);
    int*  cur     = (int*)alloc((size_t)NBKT * 4);
    int*  bktbase = (int*)alloc((size_t)(NBKT + 1) * 4);

    cast_transpose_w1<<<(IN_F * HID_F + 255) / 256, 256, 0, stream>>>(W1, w1t);
    cast_transpose_w2<<<(HID_F * OUT_F + 255) / 256, 256, 0, stream>>>(W2, w2t);
    cast_x<<<(N_NODES * IN_F / 8 + 255) / 256, 256, 0, stream>>>(x, xb);
    gemm1<<<((N_NODES + BM - 1) / BM) * 2, 256, 0, stream>>>(xb, w1t, b1, h1);
    gemm2<<<(N_NODES + 63) / 64, 256, 0, stream>>>(h1, w2t, b2, hb0);

    bs_init<<<(NBKT + 255) / 256, 256, 0, stream>>>(cur);
    bucket_scatter<<<SBLK, 256, 0, stream>>>(row, col, ew, cur, tmp);
    bkt_scan<<<1, 64, 0, stream>>>(cur, bktbase, rowptr);
    bucket_sort<<<NBKT, 256, 0, stream>>>(tmp, bktbase, rowptr, colw);

    const unsigned short* pin = hb0;
    for (int s = 0; s < 10; ++s) {
        int last = (s == 9);
        unsigned short* pout = (s & 1) ? hb0 : hb1;
        prop<<<N_NODES / 4, 256, 0, stream>>>(pin, rowptr, colw, pout, out, last);
        pin = pout;
    }
}